// Round 4
// baseline (674.056 us; speedup 1.0000x reference)
//
#include <hip/hip_runtime.h>
#include <hip/hip_bf16.h>
#include <math.h>

// Model dims
#define NB 2
#define LSEQ 1024
#define DM 512
#define FFD 2048
#define NHEAD 8
#define DKH 64
#define NLAYER 4
#define VOCAB 8000
#define NCHUNK 16           // L / 64
#define NROWS (NB * LSEQ)   // 2048
#define QS 1536             // fused QKV row stride
#define NHEADCAT 8512       // 512 (img) + 8000 (txt)
#define NHEADPAD 8576       // padded: 512 + 252*32

#define OP_NONE 0
#define OP_GELU 2
#define OP_QKV  3   // elu+1 for col<1024 (Q,K), none for V
#define OP_PART 4   // raw fp32 partial at outF + z*M*Nout (split-K)
#define OP_HEAD 5   // col<512 -> outF (img), else outF2 (txt); grid x=M-tiles!

typedef __attribute__((ext_vector_type(8))) short short8;
typedef __attribute__((ext_vector_type(4))) float f32x4;
typedef __hip_bfloat16 bf16;

// ---------------------------------------------------------------------------
// 32x32 transpose-cast tile: src (K,N) fp32 -> dst (Npad,K) bf16; n>=N -> 0.
// Vectorized: float4 loads (16B/lane), 8B stores.
// ---------------------------------------------------------------------------
__device__ __forceinline__ void cast_tile(
    const float* __restrict__ s, bf16* __restrict__ d, int K, int N,
    int n0, int k0, int tid)
{
    __shared__ float tile[32][33];
    const int r  = tid >> 3;          // k within tile, 0..31
    const int c4 = (tid & 7) * 4;     // n within tile, multiple of 4
    const int n  = n0 + c4;
    float4 v = make_float4(0.f, 0.f, 0.f, 0.f);
    if (n < N)                        // N % 4 == 0, so whole float4 in or out
        v = *(const float4*)(s + (size_t)(k0 + r) * N + n);
    tile[r][c4 + 0] = v.x; tile[r][c4 + 1] = v.y;
    tile[r][c4 + 2] = v.z; tile[r][c4 + 3] = v.w;
    __syncthreads();
    const int nr = tid >> 3;          // n-row for write
    const int kc = (tid & 7) * 4;     // k cols, multiple of 4
    bf16 o[4];
    o[0] = __float2bfloat16(tile[kc + 0][nr]);
    o[1] = __float2bfloat16(tile[kc + 1][nr]);
    o[2] = __float2bfloat16(tile[kc + 2][nr]);
    o[3] = __float2bfloat16(tile[kc + 3][nr]);
    *(unsigned long long*)(d + (size_t)(n0 + nr) * K + k0 + kc) =
        *(const unsigned long long*)o;
    __syncthreads();
}

// ---------------------------------------------------------------------------
// ONE setup dispatch: all weight transposes-casts, x_img cast, bias prep.
// ---------------------------------------------------------------------------
#define CO_QKVO 0        // 4096: Wq/Wk/Wv/Wo (4 layers x 4 x 256 tiles)
#define CO_W1   4096     // 4096
#define CO_W2   8192     // 4096
#define CO_WEI  12288    // 256
#define CO_WPI  12544    // 256
#define CO_WPT  12800    // 4032
#define CO_XIMG 16832    // 1024
#define CO_QKVB 17856    // 4
#define CO_HB   17860    // 34
#define CO_END  17894

__global__ __launch_bounds__(256) void setup_all(
    const float* __restrict__ Wq, const float* __restrict__ Wk,
    const float* __restrict__ Wv, const float* __restrict__ Wo,
    const float* __restrict__ W1, const float* __restrict__ W2,
    const float* __restrict__ Wei, const float* __restrict__ Wpi,
    const float* __restrict__ Wpt,
    bf16* __restrict__ QKVt, bf16* __restrict__ Wot,
    bf16* __restrict__ W1t, bf16* __restrict__ W2t,
    bf16* __restrict__ Weit, bf16* __restrict__ Whead,
    const float* __restrict__ x_img, bf16* __restrict__ ximgh,
    const float* __restrict__ bq, const float* __restrict__ bk,
    const float* __restrict__ bv, float* __restrict__ qkvB,
    const float* __restrict__ bpi, const float* __restrict__ bpt,
    float* __restrict__ hb)
{
    const int id = blockIdx.x;
    const int tid = threadIdx.x;

    if (id < CO_W1) {                       // QKVO 512x512 casts
        const int rel = id;
        const int z = rel >> 8, t = rel & 255;
        const int layer = z >> 2, which = z & 3;
        const float* src = (which == 0 ? Wq : which == 1 ? Wk : which == 2 ? Wv : Wo)
                           + (size_t)layer * 262144;
        bf16* dst = (which < 3)
            ? (QKVt + (size_t)layer * 786432 + (size_t)which * 262144)
            : (Wot + (size_t)layer * 262144);
        cast_tile(src, dst, 512, 512, (t & 15) * 32, (t >> 4) * 32, tid);
    } else if (id < CO_W2) {                // W1 (512,2048) x4
        const int rel = id - CO_W1;
        const int z = rel >> 10, t = rel & 1023;
        cast_tile(W1 + (size_t)z * 1048576, W1t + (size_t)z * 1048576,
                  512, 2048, (t & 63) * 32, (t >> 6) * 32, tid);
    } else if (id < CO_WEI) {               // W2 (2048,512) x4
        const int rel = id - CO_W2;
        const int z = rel >> 10, t = rel & 1023;
        cast_tile(W2 + (size_t)z * 1048576, W2t + (size_t)z * 1048576,
                  2048, 512, (t & 15) * 32, (t >> 4) * 32, tid);
    } else if (id < CO_WPI) {               // W_ei
        const int t = id - CO_WEI;
        cast_tile(Wei, Weit, 512, 512, (t & 15) * 32, (t >> 4) * 32, tid);
    } else if (id < CO_WPT) {               // W_pi -> Whead rows 0..511
        const int t = id - CO_WPI;
        cast_tile(Wpi, Whead, 512, 512, (t & 15) * 32, (t >> 4) * 32, tid);
    } else if (id < CO_XIMG) {              // W_pt -> Whead rows 512..8575
        const int t = id - CO_WPT;
        cast_tile(Wpt, Whead + 262144, 512, VOCAB,
                  (t % 252) * 32, (t / 252) * 32, tid);
    } else if (id < CO_QKVB) {              // x_img elementwise cast
        const int i = (id - CO_XIMG) * 256 + tid;   // i < 262144 (x4 floats)
        const float4 v = *(const float4*)(x_img + (size_t)i * 4);
        ximgh[(size_t)i * 4 + 0] = __float2bfloat16(v.x);
        ximgh[(size_t)i * 4 + 1] = __float2bfloat16(v.y);
        ximgh[(size_t)i * 4 + 2] = __float2bfloat16(v.z);
        ximgh[(size_t)i * 4 + 3] = __float2bfloat16(v.w);
    } else if (id < CO_HB) {                // fused QKV bias, one layer per block
        const int z = id - CO_QKVB;
        for (int j = tid; j < QS; j += 256) {
            float v;
            if (j < 512)       v = bq[z * DM + j];
            else if (j < 1024) v = bk[z * DM + j - 512];
            else               v = bv[z * DM + j - 1024];
            qkvB[z * QS + j] = v;
        }
    } else {                                // concat head bias
        const int j = (id - CO_HB) * 256 + tid;
        if (j < NHEADPAD)
            hb[j] = (j < 512) ? bpi[j] : (j < NHEADCAT ? bpt[j - 512] : 0.f);
    }
}

// ---------------------------------------------------------------------------
// BARRIER-FREE per-wave MFMA GEMM.
// One 64-thread workgroup = one wave = one 64x64 output tile with PRIVATE
// double-buffered LDS (16KB). No cross-wave sharing -> zero s_barrier in the
// K-loop (m233: stage+vmcnt+barrier was ~72% of the 4-wave structure's
// critical path; 2-stage/3-stage pipelining both measured null against it).
// Per-wave schedule (counted vmcnt, never drained mid-loop):
//   prologue: STAGE(0,k0); STAGE(1,k0+32)       // 16 loads in flight
//   iter t:   s_waitcnt vmcnt(8)                // stage t landed, t+1 flies
//             ds_read buf[t&1]; s_waitcnt lgkmcnt(0)
//             STAGE(t&1, k0+64)                 // overwrite just-read buffer
//             16x MFMA
// LDS bank-conflict fix folded in (was 8-way, 2.2M counts/dispatch):
// source-permuted staging (rule #21) — lane loads global col-group
// sl ^ ((row>>1)&3), reader XORs the same -> 2-way (free, m136).
// Occupancy: 16KB LDS -> 10 waves/CU, each an independent ILP-2 pipeline.
// OP_HEAD: x = M-tiles + bijective XCD-chunked swizzle (B-panels L2-resident,
// FETCH 36.6->21.7MB measured earlier).
// ---------------------------------------------------------------------------
__global__ __launch_bounds__(64) void wgemm(
    const bf16* __restrict__ A, const bf16* __restrict__ Bt,
    const float* __restrict__ bias, const float* __restrict__ res,
    float* __restrict__ outF, float* __restrict__ outF2,
    bf16* __restrict__ outH,
    int M, int K, int Nout, int op, int kslab)
{
    __shared__ bf16 As[2][64 * 32];
    __shared__ bf16 Bs[2][64 * 32];
    const int lane = threadIdx.x;
    const int l16 = lane & 15, quad = lane >> 4;
    const int rr = lane >> 2;           // staging row within each 16-row group
    const int sl = lane & 3;            // staging 16B slot within 64B row

    int bm, bn;
    if (op == OP_HEAD) {
        // bijective XCD-chunked swizzle (m204), x-fastest logical order:
        // each XCD gets ~536 consecutive ids = ~17 N-panels; per-XCD set
        // = B ~1.1MB + A panels < 4MB L2.
        const int gx = gridDim.x;       // = M-tiles
        const int nwg = gx * gridDim.y;
        int flat = blockIdx.y * gx + blockIdx.x;
        const int q = nwg >> 3, r = nwg & 7;
        const int xcd = flat & 7, lid = flat >> 3;
        flat = (xcd < r ? xcd * (q + 1) : r * (q + 1) + (xcd - r) * q) + lid;
        bm = (flat % gx) * 64;
        bn = (flat / gx) * 64;
    } else {
        bm = blockIdx.y * 64;           // x = N-tiles: B-panel locality per XCD
        bn = blockIdx.x * 64;           // (gx multiple of 8 keeps xcd = x%8)
    }

    f32x4 acc[4][4];
    #pragma unroll
    for (int i = 0; i < 4; ++i)
        #pragma unroll
        for (int j = 0; j < 4; ++j) acc[i][j] = (f32x4){0.f, 0.f, 0.f, 0.f};

    // swizzled global col-group: (row>>1)&3 == (rr>>1)&3 (indep. of 16-row
    // group since 8i & 3 == 0); same for the read side.
    const int csw = (sl ^ ((rr >> 1) & 3)) << 3;
    const int rsw = ((quad ^ ((l16 >> 1) & 3)) << 3);

    const bf16* gA[4];
    const bf16* gB[4];
    #pragma unroll
    for (int i = 0; i < 4; ++i) {
        gA[i] = A  + (size_t)(bm + i * 16 + rr) * K + csw;
        gB[i] = Bt + (size_t)(bn + i * 16 + rr) * K + csw;
    }

    const int kStart = blockIdx.z * kslab;
    const int kEnd = kStart + kslab;

    auto stage = [&](int buf, int k0) {
        #pragma unroll
        for (int i = 0; i < 4; ++i)
            __builtin_amdgcn_global_load_lds(
                (const __attribute__((address_space(1))) void*)(gA[i] + k0),
                (__attribute__((address_space(3))) void*)((char*)As[buf] + i * 1024),
                16, 0, 0);
        #pragma unroll
        for (int i = 0; i < 4; ++i)
            __builtin_amdgcn_global_load_lds(
                (const __attribute__((address_space(1))) void*)(gB[i] + k0),
                (__attribute__((address_space(3))) void*)((char*)Bs[buf] + i * 1024),
                16, 0, 0);
    };

    stage(0, kStart);
    if (kStart + 32 < kEnd) stage(1, kStart + 32);
    int cur = 0;
    for (int k0 = kStart; k0 < kEnd; k0 += 32) {
        if (k0 + 32 < kEnd)
            asm volatile("s_waitcnt vmcnt(8)" ::: "memory");
        else
            asm volatile("s_waitcnt vmcnt(0)" ::: "memory");
        short8 a[4], b[4];
        #pragma unroll
        for (int i = 0; i < 4; ++i)
            a[i] = *(const short8*)(As[cur] + (i * 16 + l16) * 32 + rsw);
        #pragma unroll
        for (int j = 0; j < 4; ++j)
            b[j] = *(const short8*)(Bs[cur] + (j * 16 + l16) * 32 + rsw);
        asm volatile("s_waitcnt lgkmcnt(0)" ::: "memory");  // reads landed
        if (k0 + 64 < kEnd) stage(cur, k0 + 64);            // safe to overwrite
        #pragma unroll
        for (int i = 0; i < 4; ++i)
            #pragma unroll
            for (int j = 0; j < 4; ++j)
                acc[i][j] = __builtin_amdgcn_mfma_f32_16x16x32_bf16(
                    a[i], b[j], acc[i][j], 0, 0, 0);
        cur ^= 1;
    }

    if (op == OP_PART) {
        float* dst = outF + (size_t)blockIdx.z * (size_t)M * Nout;
        #pragma unroll
        for (int j = 0; j < 4; ++j) {
            const int col = bn + j * 16 + l16;
            #pragma unroll
            for (int i = 0; i < 4; ++i)
                #pragma unroll
                for (int r = 0; r < 4; ++r) {
                    const int row = bm + i * 16 + quad * 4 + r;
                    dst[(size_t)row * Nout + col] = acc[i][j][r];
                }
        }
        return;
    }
    if (op == OP_HEAD) {
        #pragma unroll
        for (int j = 0; j < 4; ++j) {
            const int col = bn + j * 16 + l16;
            const bool cok = (col < NHEADCAT);
            const float bz = cok ? bias[col] : 0.f;
            #pragma unroll
            for (int i = 0; i < 4; ++i)
                #pragma unroll
                for (int r = 0; r < 4; ++r) {
                    const int row = bm + i * 16 + quad * 4 + r;
                    const float v = acc[i][j][r] + bz;
                    if (cok) {
                        if (col < 512) outF[(size_t)row * 512 + col] = v;
                        else           outF2[(size_t)row * VOCAB + (col - 512)] = v;
                    }
                }
        }
        return;
    }

    #pragma unroll
    for (int j = 0; j < 4; ++j) {
        const int col = bn + j * 16 + l16;
        const bool cok = (col < Nout);
        const float bz = cok ? bias[col] : 0.f;
        #pragma unroll
        for (int i = 0; i < 4; ++i) {
            #pragma unroll
            for (int r = 0; r < 4; ++r) {
                const int row = bm + i * 16 + quad * 4 + r;
                float v = acc[i][j][r] + bz;
                if (op == OP_GELU)      v = 0.5f * v * (1.f + erff(v * 0.70710678118654752f));
                else if (op == OP_QKV && col < 1024) v = (v > 0.f) ? v + 1.f : expf(v);
                if (cok) {
                    if (res)  v += res[(size_t)row * Nout + col];
                    if (outF) outF[(size_t)row * Nout + col] = v;
                    if (outH) outH[(size_t)row * Nout + col] = __float2bfloat16(v);
                }
            }
        }
    }
}

// ---------------------------------------------------------------------------
// Embedding combine. gI = x_img @ W_ei + b_ei (precomputed fp32).
// ---------------------------------------------------------------------------
__global__ __launch_bounds__(256) void embed_k(
    const float* __restrict__ gI, const int* __restrict__ xt,
    const float* __restrict__ emb,
    const float* __restrict__ mi, const float* __restrict__ mt,
    const float* __restrict__ pr, const float* __restrict__ pc,
    const float* __restrict__ pt, float* __restrict__ X, bf16* __restrict__ Xh)
{
    const int row = blockIdx.x;
    const float prv = pr[row], pcv = pc[row], ptv = pt[row];
    const float miv = mi[row], mtv = mt[row];
    const int tok = xt[row];
    const float LOG1E4 = 9.2103403719761836f;
    const float LI127 = LOG1E4 / 127.f;
    const float LI255 = LOG1E4 / 255.f;

    for (int d = threadIdx.x; d < DM; d += 256) {
        float ip;
        if (d < 128)       ip = sinf(prv * expf(-(float)d * LI127));
        else if (d < 256)  ip = cosf(prv * expf(-(float)(d - 128) * LI127));
        else if (d < 384)  ip = sinf(pcv * expf(-(float)(d - 256) * LI127));
        else               ip = cosf(pcv * expf(-(float)(d - 384) * LI127));
        float tp;
        if (d < 256) tp = sinf(ptv * expf(-(float)d * LI255));
        else         tp = cosf(ptv * expf(-(float)(d - 256) * LI255));
        const float v = miv * (gI[(size_t)row * DM + d] + ip)
                      + mtv * (emb[(size_t)tok * DM + d] + tp);
        X[(size_t)row * DM + d] = v;
        Xh[(size_t)row * DM + d] = __float2bfloat16(v);
    }
}

// ---------------------------------------------------------------------------
// Fused partial-sum + bias + residual + LayerNorm (out may alias res).
// ---------------------------------------------------------------------------
__global__ __launch_bounds__(256) void ln_red(
    const float* __restrict__ P, int nP,
    const float* __restrict__ bias, const float* __restrict__ res,
    const float* __restrict__ g, const float* __restrict__ b,
    float* __restrict__ out, bf16* __restrict__ outh)
{
    const int row = blockIdx.x;
    const int tid = threadIdx.x;
    const int lane = tid & 63, wv = tid >> 6;
    const size_t base = (size_t)row * DM;
    float x0 = res[base + tid] + bias[tid];
    float x1 = res[base + tid + 256] + bias[tid + 256];
    for (int p = 0; p < nP; ++p) {
        x0 += P[(size_t)p * 1048576 + base + tid];
        x1 += P[(size_t)p * 1048576 + base + tid + 256];
    }
    __shared__ float redA[4];
    __shared__ float redB[4];
    float s = x0 + x1;
    #pragma unroll
    for (int off = 32; off > 0; off >>= 1) s += __shfl_down(s, off);
    if (lane == 0) redA[wv] = s;
    __syncthreads();
    const float mean = (redA[0] + redA[1] + redA[2] + redA[3]) * (1.f / (float)DM);
    const float d0 = x0 - mean, d1 = x1 - mean;
    float v = d0 * d0 + d1 * d1;
    #pragma unroll
    for (int off = 32; off > 0; off >>= 1) v += __shfl_down(v, off);
    if (lane == 0) redB[wv] = v;
    __syncthreads();
    const float var = (redB[0] + redB[1] + redB[2] + redB[3]) * (1.f / (float)DM);
    const float rstd = rsqrtf(var + 1e-5f);
    const float y0 = d0 * rstd * g[tid] + b[tid];
    const float y1 = d1 * rstd * g[tid + 256] + b[tid + 256];
    out[base + tid]        = y0;
    out[base + tid + 256]  = y1;
    outh[base + tid]       = __float2bfloat16(y0);
    outh[base + tid + 256] = __float2bfloat16(y1);
}

// ---------------------------------------------------------------------------
// Chunked-parallel linear attention.
// Kernel 1: raw chunk sums S_c = K_c^T @ V_c and ksum_c. Grid (16,8,2).
// ---------------------------------------------------------------------------
__global__ __launch_bounds__(256) void attn_kv(
    const float* __restrict__ Kp, const float* __restrict__ Vp,
    float* __restrict__ S, float* __restrict__ ks)
{
    const int c = blockIdx.x, h = blockIdx.y, n = blockIdx.z;
    const int tid = threadIdx.x;
    __shared__ float sK[64][64], sV[64][64], part[4][64];

    const int lr = tid >> 4;
    const int c4 = (tid & 15) * 4;
    #pragma unroll
    for (int it = 0; it < 4; ++it) {
        const int row = it * 16 + lr;
        const size_t gb = ((size_t)(n * LSEQ + c * 64 + row)) * QS + h * DKH + c4;
        *(float4*)&sK[row][c4] = *(const float4*)(Kp + gb);
        *(float4*)&sV[row][c4] = *(const float4*)(Vp + gb);
    }
    __syncthreads();

    const int e = tid & 63, dq = tid >> 6;
    float s[16] = {};
    for (int l = 0; l < 64; ++l) {
        const float vv = sV[l][e];
        const float4 k0 = *(const float4*)&sK[l][dq * 16 + 0];
        const float4 k1 = *(const float4*)&sK[l][dq * 16 + 4];
        const float4 k2 = *(const float4*)&sK[l][dq * 16 + 8];
        const float4 k3 = *(const float4*)&sK[l][dq * 16 + 12];
        s[0]  = fmaf(k0.x, vv, s[0]);  s[1]  = fmaf(k0.y, vv, s[1]);
        s[2]  = fmaf(k0.z, vv, s[2]);  s[3]  = fmaf(k0.w, vv, s[3]);
        s[4]  = fmaf(k1.x, vv, s[4]);  s[5]  = fmaf(k1.y, vv, s[5]);
        s[6]  = fmaf(k1.z, vv, s[6]);  s[7]  = fmaf(k1.w, vv, s[7]);
        s[8]  = fmaf(k2.x, vv, s[8]);  s[9]  = fmaf(k2.y, vv, s[9]);
        s[10] = fmaf(k2.z, vv, s[10]); s[11] = fmaf(k2.w, vv, s[11]);
        s[12] = fmaf(k3.x, vv, s[12]); s[13] = fmaf(k3.y, vv, s[13]);
        s[14] = fmaf(k3.z, vv, s[14]); s[15] = fmaf(k3.w, vv, s[15]);
    }
    const size_t sb = (((size_t)(n * NHEAD + h)) * NCHUNK + c) * 4096;
    #pragma unroll
    for (int i = 0; i < 16; ++i) S[sb + (size_t)(dq * 16 + i) * 64 + e] = s[i];

    float kp = 0.f;
    #pragma unroll
    for (int i = 0; i < 16; ++i) kp += sK[dq * 16 + i][e];
    part[dq][e] = kp;
    __syncthreads();
    if (tid < 64)
        ks[(((size_t)(n * NHEAD + h)) * NCHUNK + c) * 64 + tid] =
            part[0][tid] + part[1][tid] + part[2][tid] + part[3][tid];
}

// Kernel 2: O = Q@S_pre + tril(Q@K^T)@V. Prefix S_pre is summed inline from
// the raw chunk states of chunks < c (exclusive). Grid (16,8,2).
__global__ __launch_bounds__(256) void attn_out(
    const float* __restrict__ QKV, const float* __restrict__ S,
    const float* __restrict__ ks, bf16* __restrict__ O)
{
    const int c = blockIdx.x, h = blockIdx.y, n = blockIdx.z;
    const int tid = threadIdx.x;
    __shared__ float sQt[64][64];
    __shared__ float sKt[64][64];
    __shared__ float sV [64][64];
    __shared__ float sS [64][64];
    __shared__ float sPt[64][65];
    __shared__ float skp[64];

    const size_t nhS = ((size_t)(n * NHEAD + h)) * NCHUNK * 4096;
    const size_t nhK = ((size_t)(n * NHEAD + h)) * NCHUNK * 64;

    // inline exclusive prefix of chunk states
    {
        float4 aS[4] = {};
        for (int cc = 0; cc < c; ++cc) {
            const float* Sc = S + nhS + (size_t)cc * 4096;
            #pragma unroll
            for (int i = 0; i < 4; ++i) {
                const float4 t = *(const float4*)(Sc + i * 1024 + tid * 4);
                aS[i].x += t.x; aS[i].y += t.y; aS[i].z += t.z; aS[i].w += t.w;
            }
        }
        float* sSf = &sS[0][0];
        #pragma unroll
        for (int i = 0; i < 4; ++i)
            *(float4*)(sSf + i * 1024 + tid * 4) = aS[i];
        if (tid < 64) {
            float kp = 0.f;
            for (int cc = 0; cc < c; ++cc) kp += ks[nhK + cc * 64 + tid];
            skp[tid] = kp;
        }
    }

    const int lr = tid >> 4;
    const int c4 = (tid & 15) * 4;
    #pragma unroll
    for (int it = 0; it < 4; ++it) {
        const int row = it * 16 + lr;
        const size_t gb = ((size_t)(n * LSEQ + c * 64 + row)) * QS + h * DKH + c4;
        const float4 q4 = *(const float4*)(QKV + gb);
        const float4 k4 = *(const float4*)(QKV + gb + 512);
        const float4 v4 = *(const float4*)(QKV + gb + 1024);
        sQt[c4 + 0][row] = q4.x; sQt[c4 + 1][row] = q4.y;
        sQt[c4 + 2][row] = q4.z; sQt[c4 + 3][row] = q4.w;
        sKt[c4 + 0][row] = k4.x; sKt[c4 + 1][row] = k4.y;
        sKt[c4 + 2][row] = k4.z; sKt[c4 + 3][row] = k4.w;
        *(float4*)&sV[row][c4] = v4;
    }
    __syncthreads();

    const int m4 = (tid & 15) * 4;
    const int lg = tid >> 4;
    {
        float p[4][4] = {};
        for (int d = 0; d < 64; ++d) {
            const float4 k4 = *(const float4*)&sKt[d][m4];
            const float4 q4 = *(const float4*)&sQt[d][lg * 4];
            p[0][0] = fmaf(q4.x, k4.x, p[0][0]); p[0][1] = fmaf(q4.x, k4.y, p[0][1]);
            p[0][2] = fmaf(q4.x, k4.z, p[0][2]); p[0][3] = fmaf(q4.x, k4.w, p[0][3]);
            p[1][0] = fmaf(q4.y, k4.x, p[1][0]); p[1][1] = fmaf(q4.y, k4.y, p[1][1]);
            p[1][2] = fmaf(q4.y, k4.z, p[1][2]); p[1][3] = fmaf(q4.y, k4.w, p[1][3]);
            p[2][0] = fmaf(q4.z, k4.x, p[2][0]); p[2][1] = fmaf(q4.z, k4.y, p[2][1]);
            p[2][2] = fmaf(q4.z, k4.z, p[2][2]); p[2][3] = fmaf(q4.z, k4.w, p[2][3]);
            p[3][0] = fmaf(q4.w, k4.x, p[3][0]); p[3][1] = fmaf(q4.w, k4.y, p[3][1]);
            p[3][2] = fmaf(q4.w, k4.z, p[3][2]); p[3][3] = fmaf(q4.w, k4.w, p[3][3]);
        }
        #pragma unroll
        for (int jj = 0; jj < 4; ++jj)
            #pragma unroll
            for (int j = 0; j < 4; ++j)
                sPt[m4 + jj][lg * 4 + j] = p[j][jj];
    }
    __syncthreads();

    float acc[4][4] = {};
    float z[4] = {};
    const int lmax = lg * 4 + 3;
    for (int m = 0; m <= lmax; ++m) {
        const float4 v4 = *(const float4*)&sV[m][m4];
        #pragma unroll
        for (int j = 0; j < 4; ++j) {
            const int l = lg * 4 + j;
            float p = sPt[m][l];
            p = (m <= l) ? p : 0.f;
            z[j] += p;
            acc[j][0] = fmaf(p, v4.x, acc[j][0]);
            acc[j][1] = fmaf(p, v4.y, acc[j][1]);
            acc[j][2] = fmaf(p, v4.z, acc[j][2]);
            acc[j][3] = fmaf(p, v4.w, acc[j][3]);
        }
    }
    for (int d = 0; d < 64; ++d) {
        const float4 s4 = *(const float4*)&sS[d][m4];
        const float4 q4 = *(const float4*)&sQt[d][lg * 4];
        const float kp = skp[d];
        z[0] = fmaf(q4.x, kp, z[0]); z[1] = fmaf(q4.y, kp, z[1]);
        z[2] = fmaf(q4.z, kp, z[2]); z[3] = fmaf(q4.w, kp, z[3]);
        acc[0][0] = fmaf(q4.x, s4.x, acc[0][0]); acc[0][1] = fmaf(q4.x, s4.y, acc[0][1]);
        acc[0][2] = fmaf(q4.x, s4.z, acc[0][2]); acc[0][3] = fmaf(q4.x, s4.w, acc[0][3]);
        acc[1][0] = fmaf(q4.y, s4.x, acc[1][0]); acc[1][1] = fmaf(q4.y, s4.y, acc[1][1]);
        acc[1][2] = fmaf(q4.y, s4.z, acc[1][2]); acc[1][3] = fmaf(q4.y, s4.w, acc[1][3]);
        acc[2][0] = fmaf(q4.z, s4.x, acc[2][0]); acc[2][1] = fmaf(q4.z, s4.y, acc[2][1]);
        acc[2][2] = fmaf(q4.z, s4.z, acc[2][2]); acc[2][3] = fmaf(q4.z, s4.w, acc[2][3]);
        acc[3][0] = fmaf(q4.w, s4.x, acc[3][0]); acc[3][1] = fmaf(q4.w, s4.y, acc[3][1]);
        acc[3][2] = fmaf(q4.w, s4.z, acc[3][2]); acc[3][3] = fmaf(q4.w, s4.w, acc[3][3]);
    }
    #pragma unroll
    for (int j = 0; j < 4; ++j) {
        const int l = lg * 4 + j;
        const float rz = 1.f / (z[j] + 1e-6f);
        const size_t ob = ((size_t)(n * LSEQ + c * 64 + l)) * DM + h * DKH + m4;
        O[ob + 0] = __float2bfloat16(acc[j][0] * rz);
        O[ob + 1] = __float2bfloat16(acc[j][1] * rz);
        O[ob + 2] = __float2bfloat16(acc[j][2] * rz);
        O[ob + 3] = __float2bfloat16(acc[j][3] * rz);
    }
}

// ---------------------------------------------------------------------------
extern "C" void kernel_launch(void* const* d_in, const int* in_sizes, int n_in,
                              void* d_out, int out_size, void* d_ws, size_t ws_size,
                              hipStream_t stream)
{
    const float* x_img   = (const float*)d_in[0];
    const int*   x_txt   = (const int*)  d_in[1];
    const float* mask_i  = (const float*)d_in[2];
    const float* mask_t  = (const float*)d_in[3];
    const float* pos_r   = (const float*)d_in[4];
    const float* pos_c   = (const float*)d_in[5];
    const float* pos_t   = (const float*)d_in[6];
    const float* W_ei    = (const float*)d_in[7];
    const float* b_ei    = (const float*)d_in[8];
    const float* emb_txt = (const float*)d_in[9];
    const float* Wq      = (const float*)d_in[10];
    const float* bq      = (const float*)d_in[11];
    const float* Wk      = (const float*)d_in[12];
    const float* bk      = (const float*)d_in[13];
    const float* Wv      = (const float*)d_in[14];
    const float* bv      = (const float*)d_in[15];
    const float* Wo      = (const float*)d_in[16];
    const float* bo      = (const float*)d_in[17];
    const float* W1      = (const float*)d_in[18];
    const float* b1      = (const float*)d_in[19];
    const float* W2      = (const float*)d_in[20];
    const float* b2      = (const float*)d_in[21];
    const float* ln1_s   = (const float*)d_in[22];
    const float* ln1_b   = (const float*)d_in[23];
    const float* ln2_s   = (const float*)d_in[24];
    const float* ln2_b   = (const float*)d_in[25];
    const float* W_pi    = (const float*)d_in[26];
    const float* b_pi    = (const float*)d_in[27];
    const float* W_pt    = (const float*)d_in[28];
    const float* b_pt    = (const float*)d_in[29];

    float* ws = (float*)d_ws;
    size_t off = 0;
    auto alloc = [&](size_t nfloats) { float* p = ws + off; off += nfloats; return p; };

    float* Xb   = alloc(1048576);           // activations fp32 (N,L,D)
    float* Pb   = alloc(4194304);           // split-K partials / embed scratch
    float* QKVb = alloc(3145728);           // fused QKV fp32 (N,L,1536)
    float* Sb   = alloc(1048576);           // raw chunk KV sums
    float* ksb  = alloc(16384);
    float* qkvB = alloc(4 * QS);            // fused QKV bias
    float* hb   = alloc(8704);              // concat head bias
    bf16* Xh    = (bf16*)alloc(524288);     // activations bf16
    bf16* Ob    = (bf16*)alloc(524288);     // attention out bf16
    bf16* Tb    = (bf16*)alloc(2097152);    // FF intermediate bf16 (N,L,FF)
    bf16* ximgh = (bf16*)alloc(524288);
    bf16* QKVt  = (bf16*)alloc(1572864);    // (NL,1536,512)
    bf16* Wot   = (bf16*)alloc(524288);     // (NL,512,512)
    bf16* W1t   = (bf16*)alloc(2097152);    // (NL,2048,512)
    bf16* W2t   = (bf16*)alloc(2097152);    // (NL,512,2048)
    bf16* Weit  = (bf16*)alloc(131072);     // (512,512)
    bf16* Whead = (bf16*)alloc(2195456);    // (8576,512)

    const dim3 blk(256);
    const dim3 wblk(64);
    const dim3 gAttn(NCHUNK, NHEAD, NB);

    // ---- one setup dispatch: all casts + biases ----
    setup_all<<<dim3(CO_END), blk, 0, stream>>>(
        Wq, Wk, Wv, Wo, W1, W2, W_ei, W_pi, W_pt,
        QKVt, Wot, W1t, W2t, Weit, Whead,
        x_img, ximgh, bq, bk, bv, qkvB, b_pi, b_pt, hb);

    // ---- embedding ----
    wgemm<<<dim3(8, 32), wblk, 0, stream>>>(
        ximgh, Weit, b_ei, nullptr, Pb, nullptr, nullptr, NROWS, 512, 512, OP_NONE, 512);
    embed_k<<<NROWS, blk, 0, stream>>>(Pb, x_txt, emb_txt, mask_i, mask_t,
                                       pos_r, pos_c, pos_t, Xb, Xh);

    for (int i = 0; i < NLAYER; ++i) {
        // fused QKV projection (elu+1 on Q,K cols)
        wgemm<<<dim3(24, 32), wblk, 0, stream>>>(
            Xh, QKVt + (size_t)i * 786432, qkvB + i * QS, nullptr,
            QKVb, nullptr, nullptr, NROWS, 512, QS, OP_QKV, 512);

        attn_kv<<<gAttn, blk, 0, stream>>>(QKVb + 512, QKVb + 1024, Sb, ksb);
        attn_out<<<gAttn, blk, 0, stream>>>(QKVb, Sb, ksb, Ob);

        // out proj (split-K=2 partials) -> fused reduce+residual+LN1
        wgemm<<<dim3(8, 32, 2), wblk, 0, stream>>>(
            Ob, Wot + (size_t)i * 262144, nullptr, nullptr,
            Pb, nullptr, nullptr, NROWS, 512, 512, OP_PART, 256);
        ln_red<<<NROWS, blk, 0, stream>>>(Pb, 2, bo + (size_t)i * DM, Xb,
                                          ln1_s + (size_t)i * DM,
                                          ln1_b + (size_t)i * DM, Xb, Xh);

        // FF1 (gelu fused) -> FF2 (split-K=4) -> fused reduce+residual+LN2
        wgemm<<<dim3(32, 32), wblk, 0, stream>>>(
            Xh, W1t + (size_t)i * 1048576, b1 + (size_t)i * FFD, nullptr,
            nullptr, nullptr, Tb, NROWS, 512, FFD, OP_GELU, 512);
        wgemm<<<dim3(8, 32, 4), wblk, 0, stream>>>(
            Tb, W2t + (size_t)i * 1048576, nullptr, nullptr,
            Pb, nullptr, nullptr, NROWS, 2048, 512, OP_PART, 512);
        ln_red<<<NROWS, blk, 0, stream>>>(Pb, 4, b2 + (size_t)i * DM, Xb,
                                          ln2_s + (size_t)i * DM,
                                          ln2_b + (size_t)i * DM, Xb, Xh);
    }

    // ---- merged heads, x = M-tiles + XCD-chunked swizzle ----
    float* out = (float*)d_out;
    wgemm<<<dim3(32, 134), wblk, 0, stream>>>(
        Xh, Whead, hb, nullptr, out, out + 1048576, nullptr,
        NROWS, 512, NHEADCAT, OP_HEAD, 512);
}

// Round 5
// 642.007 us; speedup vs baseline: 1.0499x; 1.0499x over previous
//
#include <hip/hip_runtime.h>
#include <hip/hip_bf16.h>
#include <math.h>

// Model dims
#define NB 2
#define LSEQ 1024
#define DM 512
#define FFD 2048
#define NHEAD 8
#define DKH 64
#define NLAYER 4
#define VOCAB 8000
#define NCHUNK 16           // L / 64
#define NROWS (NB * LSEQ)   // 2048
#define QS 1536             // fused QKV row stride
#define NHEADCAT 8512       // 512 (img) + 8000 (txt)
#define NHEADPAD 8576       // padded: 512 + 252*32

#define OP_NONE 0
#define OP_GELU 2
#define OP_QKV  3   // elu+1 for col<1024 (Q,K), none for V
#define OP_PART 4   // raw fp32 partial at outF + z*M*Nout (split-K)
#define OP_HEAD 5   // col<512 -> outF (img), else outF2 (txt); grid x=M-tiles!

typedef __attribute__((ext_vector_type(8))) short short8;
typedef __attribute__((ext_vector_type(4))) float f32x4;
typedef __hip_bfloat16 bf16;

// ---------------------------------------------------------------------------
// 32x32 transpose-cast tile: src (K,N) fp32 -> dst (Npad,K) bf16; n>=N -> 0.
// Vectorized: float4 loads (16B/lane), 8B stores.
// ---------------------------------------------------------------------------
__device__ __forceinline__ void cast_tile(
    const float* __restrict__ s, bf16* __restrict__ d, int K, int N,
    int n0, int k0, int tid)
{
    __shared__ float tile[32][33];
    const int r  = tid >> 3;          // k within tile, 0..31
    const int c4 = (tid & 7) * 4;     // n within tile, multiple of 4
    const int n  = n0 + c4;
    float4 v = make_float4(0.f, 0.f, 0.f, 0.f);
    if (n < N)                        // N % 4 == 0, so whole float4 in or out
        v = *(const float4*)(s + (size_t)(k0 + r) * N + n);
    tile[r][c4 + 0] = v.x; tile[r][c4 + 1] = v.y;
    tile[r][c4 + 2] = v.z; tile[r][c4 + 3] = v.w;
    __syncthreads();
    const int nr = tid >> 3;          // n-row for write
    const int kc = (tid & 7) * 4;     // k cols, multiple of 4
    bf16 o[4];
    o[0] = __float2bfloat16(tile[kc + 0][nr]);
    o[1] = __float2bfloat16(tile[kc + 1][nr]);
    o[2] = __float2bfloat16(tile[kc + 2][nr]);
    o[3] = __float2bfloat16(tile[kc + 3][nr]);
    *(unsigned long long*)(d + (size_t)(n0 + nr) * K + k0 + kc) =
        *(const unsigned long long*)o;
    __syncthreads();
}

// ---------------------------------------------------------------------------
// ONE setup dispatch: all weight transposes-casts, x_img cast, bias prep.
// ---------------------------------------------------------------------------
#define CO_QKVO 0        // 4096: Wq/Wk/Wv/Wo (4 layers x 4 x 256 tiles)
#define CO_W1   4096     // 4096
#define CO_W2   8192     // 4096
#define CO_WEI  12288    // 256
#define CO_WPI  12544    // 256
#define CO_WPT  12800    // 4032
#define CO_XIMG 16832    // 1024
#define CO_QKVB 17856    // 4
#define CO_HB   17860    // 34
#define CO_END  17894

__global__ __launch_bounds__(256) void setup_all(
    const float* __restrict__ Wq, const float* __restrict__ Wk,
    const float* __restrict__ Wv, const float* __restrict__ Wo,
    const float* __restrict__ W1, const float* __restrict__ W2,
    const float* __restrict__ Wei, const float* __restrict__ Wpi,
    const float* __restrict__ Wpt,
    bf16* __restrict__ QKVt, bf16* __restrict__ Wot,
    bf16* __restrict__ W1t, bf16* __restrict__ W2t,
    bf16* __restrict__ Weit, bf16* __restrict__ Whead,
    const float* __restrict__ x_img, bf16* __restrict__ ximgh,
    const float* __restrict__ bq, const float* __restrict__ bk,
    const float* __restrict__ bv, float* __restrict__ qkvB,
    const float* __restrict__ bpi, const float* __restrict__ bpt,
    float* __restrict__ hb)
{
    const int id = blockIdx.x;
    const int tid = threadIdx.x;

    if (id < CO_W1) {                       // QKVO 512x512 casts
        const int rel = id;
        const int z = rel >> 8, t = rel & 255;
        const int layer = z >> 2, which = z & 3;
        const float* src = (which == 0 ? Wq : which == 1 ? Wk : which == 2 ? Wv : Wo)
                           + (size_t)layer * 262144;
        bf16* dst = (which < 3)
            ? (QKVt + (size_t)layer * 786432 + (size_t)which * 262144)
            : (Wot + (size_t)layer * 262144);
        cast_tile(src, dst, 512, 512, (t & 15) * 32, (t >> 4) * 32, tid);
    } else if (id < CO_W2) {                // W1 (512,2048) x4
        const int rel = id - CO_W1;
        const int z = rel >> 10, t = rel & 1023;
        cast_tile(W1 + (size_t)z * 1048576, W1t + (size_t)z * 1048576,
                  512, 2048, (t & 63) * 32, (t >> 6) * 32, tid);
    } else if (id < CO_WEI) {               // W2 (2048,512) x4
        const int rel = id - CO_W2;
        const int z = rel >> 10, t = rel & 1023;
        cast_tile(W2 + (size_t)z * 1048576, W2t + (size_t)z * 1048576,
                  2048, 512, (t & 15) * 32, (t >> 4) * 32, tid);
    } else if (id < CO_WPI) {               // W_ei
        const int t = id - CO_WEI;
        cast_tile(Wei, Weit, 512, 512, (t & 15) * 32, (t >> 4) * 32, tid);
    } else if (id < CO_WPT) {               // W_pi -> Whead rows 0..511
        const int t = id - CO_WPI;
        cast_tile(Wpi, Whead, 512, 512, (t & 15) * 32, (t >> 4) * 32, tid);
    } else if (id < CO_XIMG) {              // W_pt -> Whead rows 512..8575
        const int t = id - CO_WPT;
        cast_tile(Wpt, Whead + 262144, 512, VOCAB,
                  (t % 252) * 32, (t / 252) * 32, tid);
    } else if (id < CO_QKVB) {              // x_img elementwise cast
        const int i = (id - CO_XIMG) * 256 + tid;   // i < 262144 (x4 floats)
        const float4 v = *(const float4*)(x_img + (size_t)i * 4);
        ximgh[(size_t)i * 4 + 0] = __float2bfloat16(v.x);
        ximgh[(size_t)i * 4 + 1] = __float2bfloat16(v.y);
        ximgh[(size_t)i * 4 + 2] = __float2bfloat16(v.z);
        ximgh[(size_t)i * 4 + 3] = __float2bfloat16(v.w);
    } else if (id < CO_HB) {                // fused QKV bias, one layer per block
        const int z = id - CO_QKVB;
        for (int j = tid; j < QS; j += 256) {
            float v;
            if (j < 512)       v = bq[z * DM + j];
            else if (j < 1024) v = bk[z * DM + j - 512];
            else               v = bv[z * DM + j - 1024];
            qkvB[z * QS + j] = v;
        }
    } else {                                // concat head bias
        const int j = (id - CO_HB) * 256 + tid;
        if (j < NHEADPAD)
            hb[j] = (j < 512) ? bpi[j] : (j < NHEADCAT ? bpt[j - 512] : 0.f);
    }
}

// ---------------------------------------------------------------------------
// HEAD GEMM (best-measured config, round-2): 256-thread 4-wave 128x128 tile,
// 2-stage double-buffer, counted vmcnt, raw s_barrier. 46us measured.
// Transposed grid (x = M-tiles) + bijective XCD-chunked swizzle
// (FETCH 36.6->21.7MB measured; B-panels L2-resident).
// ---------------------------------------------------------------------------
template<int BM, int BN>
__global__ __launch_bounds__(256) void gemm16(
    const bf16* __restrict__ A, const bf16* __restrict__ Bt,
    const float* __restrict__ bias,
    float* __restrict__ outF, float* __restrict__ outF2,
    int M, int K, int Nout, int kslab)
{
    constexpr int WM = BM / 2, WN = BN / 2, MI = WM / 16, NI = WN / 16;
    constexpr int LA = BM / 64, LB = BN / 64;
    constexpr int NL = LA + LB;
    __shared__ bf16 As[2][BM * 32];
    __shared__ bf16 Bs[2][BN * 32];
    const int tid = threadIdx.x;
    const int lane = tid & 63;
    const int wave = tid >> 6;
    const int wm = (wave >> 1) * WM, wn = (wave & 1) * WN;

    // bijective XCD-chunked swizzle (m204), x-fastest logical order
    int bxi, byi;
    {
        const int gx = gridDim.x;
        const int nwg = gx * gridDim.y;
        int flat = blockIdx.y * gx + blockIdx.x;
        const int q = nwg >> 3, r = nwg & 7;
        const int xcd = flat & 7, lid = flat >> 3;
        flat = (xcd < r ? xcd * (q + 1) : r * (q + 1) + (xcd - r) * q) + lid;
        bxi = flat % gx;
        byi = flat / gx;
    }
    const int bm = bxi * BM;
    const int bn = byi * BN;
    const int l16 = lane & 15, quad = lane >> 4;

    const int rA = tid >> 2;
    const int c8 = (tid & 3) << 3;

    f32x4 acc[MI][NI];
    #pragma unroll
    for (int i = 0; i < MI; ++i)
        #pragma unroll
        for (int j = 0; j < NI; ++j) acc[i][j] = (f32x4){0.f, 0.f, 0.f, 0.f};

    const bf16* gA = A  + (size_t)(bm + rA) * K + c8;
    const bf16* gB = Bt + (size_t)(bn + rA) * K + c8;
    const int ldsWaveOff = wave * 1024;

    const int kStart = 0;
    const int kEnd = kslab;

    auto stage = [&](int buf, int k0) {
        #pragma unroll
        for (int i = 0; i < LA; ++i)
            __builtin_amdgcn_global_load_lds(
                (const __attribute__((address_space(1))) void*)(gA + (size_t)i * 64 * K + k0),
                (__attribute__((address_space(3))) void*)((char*)As[buf] + i * 4096 + ldsWaveOff),
                16, 0, 0);
        #pragma unroll
        for (int i = 0; i < LB; ++i)
            __builtin_amdgcn_global_load_lds(
                (const __attribute__((address_space(1))) void*)(gB + (size_t)i * 64 * K + k0),
                (__attribute__((address_space(3))) void*)((char*)Bs[buf] + i * 4096 + ldsWaveOff),
                16, 0, 0);
    };

    stage(0, kStart);
    int cur = 0;
    for (int k0 = kStart; k0 < kEnd; k0 += 32) {
        const bool hasNext = (k0 + 32 < kEnd);
        if (hasNext) {
            stage(cur ^ 1, k0 + 32);
            asm volatile("s_waitcnt vmcnt(%0)" :: "n"(NL) : "memory");
        } else {
            asm volatile("s_waitcnt vmcnt(0)" ::: "memory");
        }
        __builtin_amdgcn_s_barrier();
        short8 a[MI], b[NI];
        #pragma unroll
        for (int i = 0; i < MI; ++i)
            a[i] = *(const short8*)(As[cur] + (size_t)(wm + i * 16 + l16) * 32 + quad * 8);
        #pragma unroll
        for (int j = 0; j < NI; ++j)
            b[j] = *(const short8*)(Bs[cur] + (size_t)(wn + j * 16 + l16) * 32 + quad * 8);
        #pragma unroll
        for (int i = 0; i < MI; ++i)
            #pragma unroll
            for (int j = 0; j < NI; ++j)
                acc[i][j] = __builtin_amdgcn_mfma_f32_16x16x32_bf16(
                    a[i], b[j], acc[i][j], 0, 0, 0);
        __builtin_amdgcn_s_barrier();
        cur ^= 1;
    }

    // OP_HEAD epilogue
    #pragma unroll
    for (int j = 0; j < NI; ++j) {
        const int col = bn + wn + j * 16 + l16;
        const bool cok = (col < NHEADCAT);
        const float bz = cok ? bias[col] : 0.f;
        #pragma unroll
        for (int i = 0; i < MI; ++i)
            #pragma unroll
            for (int r = 0; r < 4; ++r) {
                const int row = bm + wm + i * 16 + quad * 4 + r;
                const float v = acc[i][j][r] + bz;
                if (cok) {
                    if (col < 512) outF[(size_t)row * 512 + col] = v;
                    else           outF2[(size_t)row * VOCAB + (col - 512)] = v;
                }
            }
    }
}

// ---------------------------------------------------------------------------
// LAYER GEMM: 1-wave 32x32-tile barrier-free kernel for small GEMMs.
// The layer GEMMs were GRID-BOUND (384-512 blocks = 1.5-2 blocks/CU = ~6
// waves/CU); three pipeline variants all left waves idle ~87% on load
// latency (VALUBusy~13%=issue work). Fix per roofline table: smaller tiles,
// bigger grid. 32x32/wave -> 2048-4096 waves/dispatch = 8-16 waves/CU.
// Private 8KB LDS, 2-stage counted vmcnt, zero barriers, conflict-free
// swizzle (verified 0 conflicts in round 4).
// ---------------------------------------------------------------------------
__global__ __launch_bounds__(64) void wgemm32(
    const bf16* __restrict__ A, const bf16* __restrict__ Bt,
    const float* __restrict__ bias,
    float* __restrict__ outF, bf16* __restrict__ outH,
    int M, int K, int Nout, int op, int kslab)
{
    __shared__ bf16 As[2][32 * 32];
    __shared__ bf16 Bs[2][32 * 32];
    const int lane = threadIdx.x;
    const int l16 = lane & 15, quad = lane >> 4;
    const int bm = blockIdx.y * 32;
    const int bn = blockIdx.x * 32;

    f32x4 acc[2][2];
    #pragma unroll
    for (int i = 0; i < 2; ++i)
        #pragma unroll
        for (int j = 0; j < 2; ++j) acc[i][j] = (f32x4){0.f, 0.f, 0.f, 0.f};

    // conflict-free swizzle (same involution as round 4, measured 0 conflicts)
    const int rr  = lane >> 2;                         // row in 16-row group
    const int csw = ((lane & 3) ^ ((lane >> 3) & 3)) << 3;
    const int rsw = (quad ^ ((l16 >> 1) & 3)) << 3;

    const bf16* gA[2];
    const bf16* gB[2];
    #pragma unroll
    for (int i = 0; i < 2; ++i) {
        gA[i] = A  + (size_t)(bm + i * 16 + rr) * K + csw;
        gB[i] = Bt + (size_t)(bn + i * 16 + rr) * K + csw;
    }

    const int kStart = blockIdx.z * kslab;
    const int kEnd = kStart + kslab;

    auto stage = [&](int buf, int k0) {
        #pragma unroll
        for (int i = 0; i < 2; ++i)
            __builtin_amdgcn_global_load_lds(
                (const __attribute__((address_space(1))) void*)(gA[i] + k0),
                (__attribute__((address_space(3))) void*)((char*)As[buf] + i * 1024),
                16, 0, 0);
        #pragma unroll
        for (int i = 0; i < 2; ++i)
            __builtin_amdgcn_global_load_lds(
                (const __attribute__((address_space(1))) void*)(gB[i] + k0),
                (__attribute__((address_space(3))) void*)((char*)Bs[buf] + i * 1024),
                16, 0, 0);
    };

    stage(0, kStart);
    if (kStart + 32 < kEnd) stage(1, kStart + 32);
    int cur = 0;
    for (int k0 = kStart; k0 < kEnd; k0 += 32) {
        if (k0 + 32 < kEnd)
            asm volatile("s_waitcnt vmcnt(4)" ::: "memory");
        else
            asm volatile("s_waitcnt vmcnt(0)" ::: "memory");
        short8 a[2], b[2];
        #pragma unroll
        for (int i = 0; i < 2; ++i)
            a[i] = *(const short8*)(As[cur] + (i * 16 + l16) * 32 + rsw);
        #pragma unroll
        for (int j = 0; j < 2; ++j)
            b[j] = *(const short8*)(Bs[cur] + (j * 16 + l16) * 32 + rsw);
        asm volatile("s_waitcnt lgkmcnt(0)" ::: "memory");
        if (k0 + 64 < kEnd) stage(cur, k0 + 64);
        #pragma unroll
        for (int i = 0; i < 2; ++i)
            #pragma unroll
            for (int j = 0; j < 2; ++j)
                acc[i][j] = __builtin_amdgcn_mfma_f32_16x16x32_bf16(
                    a[i], b[j], acc[i][j], 0, 0, 0);
        cur ^= 1;
    }

    if (op == OP_PART) {
        float* dst = outF + (size_t)blockIdx.z * (size_t)M * Nout;
        #pragma unroll
        for (int j = 0; j < 2; ++j) {
            const int col = bn + j * 16 + l16;
            #pragma unroll
            for (int i = 0; i < 2; ++i)
                #pragma unroll
                for (int r = 0; r < 4; ++r) {
                    const int row = bm + i * 16 + quad * 4 + r;
                    dst[(size_t)row * Nout + col] = acc[i][j][r];
                }
        }
        return;
    }

    #pragma unroll
    for (int j = 0; j < 2; ++j) {
        const int col = bn + j * 16 + l16;
        const float bz = bias ? bias[col] : 0.f;
        #pragma unroll
        for (int i = 0; i < 2; ++i) {
            #pragma unroll
            for (int r = 0; r < 4; ++r) {
                const int row = bm + i * 16 + quad * 4 + r;
                float v = acc[i][j][r] + bz;
                if (op == OP_GELU)      v = 0.5f * v * (1.f + erff(v * 0.70710678118654752f));
                else if (op == OP_QKV && col < 1024) v = (v > 0.f) ? v + 1.f : expf(v);
                if (outF) outF[(size_t)row * Nout + col] = v;
                if (outH) outH[(size_t)row * Nout + col] = __float2bfloat16(v);
            }
        }
    }
}

// ---------------------------------------------------------------------------
// Embedding combine. gI = x_img @ W_ei + b_ei (precomputed fp32).
// ---------------------------------------------------------------------------
__global__ __launch_bounds__(256) void embed_k(
    const float* __restrict__ gI, const int* __restrict__ xt,
    const float* __restrict__ emb,
    const float* __restrict__ mi, const float* __restrict__ mt,
    const float* __restrict__ pr, const float* __restrict__ pc,
    const float* __restrict__ pt, float* __restrict__ X, bf16* __restrict__ Xh)
{
    const int row = blockIdx.x;
    const float prv = pr[row], pcv = pc[row], ptv = pt[row];
    const float miv = mi[row], mtv = mt[row];
    const int tok = xt[row];
    const float LOG1E4 = 9.2103403719761836f;
    const float LI127 = LOG1E4 / 127.f;
    const float LI255 = LOG1E4 / 255.f;

    for (int d = threadIdx.x; d < DM; d += 256) {
        float ip;
        if (d < 128)       ip = sinf(prv * expf(-(float)d * LI127));
        else if (d < 256)  ip = cosf(prv * expf(-(float)(d - 128) * LI127));
        else if (d < 384)  ip = sinf(pcv * expf(-(float)(d - 256) * LI127));
        else               ip = cosf(pcv * expf(-(float)(d - 384) * LI127));
        float tp;
        if (d < 256) tp = sinf(ptv * expf(-(float)d * LI255));
        else         tp = cosf(ptv * expf(-(float)(d - 256) * LI255));
        const float v = miv * (gI[(size_t)row * DM + d] + ip)
                      + mtv * (emb[(size_t)tok * DM + d] + tp);
        X[(size_t)row * DM + d] = v;
        Xh[(size_t)row * DM + d] = __float2bfloat16(v);
    }
}

// ---------------------------------------------------------------------------
// Fused partial-sum + bias + residual + LayerNorm (out may alias res).
// ---------------------------------------------------------------------------
__global__ __launch_bounds__(256) void ln_red(
    const float* __restrict__ P, int nP,
    const float* __restrict__ bias, const float* __restrict__ res,
    const float* __restrict__ g, const float* __restrict__ b,
    float* __restrict__ out, bf16* __restrict__ outh)
{
    const int row = blockIdx.x;
    const int tid = threadIdx.x;
    const int lane = tid & 63, wv = tid >> 6;
    const size_t base = (size_t)row * DM;
    float x0 = res[base + tid] + bias[tid];
    float x1 = res[base + tid + 256] + bias[tid + 256];
    for (int p = 0; p < nP; ++p) {
        x0 += P[(size_t)p * 1048576 + base + tid];
        x1 += P[(size_t)p * 1048576 + base + tid + 256];
    }
    __shared__ float redA[4];
    __shared__ float redB[4];
    float s = x0 + x1;
    #pragma unroll
    for (int off = 32; off > 0; off >>= 1) s += __shfl_down(s, off);
    if (lane == 0) redA[wv] = s;
    __syncthreads();
    const float mean = (redA[0] + redA[1] + redA[2] + redA[3]) * (1.f / (float)DM);
    const float d0 = x0 - mean, d1 = x1 - mean;
    float v = d0 * d0 + d1 * d1;
    #pragma unroll
    for (int off = 32; off > 0; off >>= 1) v += __shfl_down(v, off);
    if (lane == 0) redB[wv] = v;
    __syncthreads();
    const float var = (redB[0] + redB[1] + redB[2] + redB[3]) * (1.f / (float)DM);
    const float rstd = rsqrtf(var + 1e-5f);
    const float y0 = d0 * rstd * g[tid] + b[tid];
    const float y1 = d1 * rstd * g[tid + 256] + b[tid + 256];
    out[base + tid]        = y0;
    out[base + tid + 256]  = y1;
    outh[base + tid]       = __float2bfloat16(y0);
    outh[base + tid + 256] = __float2bfloat16(y1);
}

// ---------------------------------------------------------------------------
// Chunked-parallel linear attention.
// Kernel 1: raw chunk sums S_c = K_c^T @ V_c and ksum_c. Grid (16,8,2).
// ---------------------------------------------------------------------------
__global__ __launch_bounds__(256) void attn_kv(
    const float* __restrict__ Kp, const float* __restrict__ Vp,
    float* __restrict__ S, float* __restrict__ ks)
{
    const int c = blockIdx.x, h = blockIdx.y, n = blockIdx.z;
    const int tid = threadIdx.x;
    __shared__ float sK[64][64], sV[64][64], part[4][64];

    const int lr = tid >> 4;
    const int c4 = (tid & 15) * 4;
    #pragma unroll
    for (int it = 0; it < 4; ++it) {
        const int row = it * 16 + lr;
        const size_t gb = ((size_t)(n * LSEQ + c * 64 + row)) * QS + h * DKH + c4;
        *(float4*)&sK[row][c4] = *(const float4*)(Kp + gb);
        *(float4*)&sV[row][c4] = *(const float4*)(Vp + gb);
    }
    __syncthreads();

    const int e = tid & 63, dq = tid >> 6;
    float s[16] = {};
    for (int l = 0; l < 64; ++l) {
        const float vv = sV[l][e];
        const float4 k0 = *(const float4*)&sK[l][dq * 16 + 0];
        const float4 k1 = *(const float4*)&sK[l][dq * 16 + 4];
        const float4 k2 = *(const float4*)&sK[l][dq * 16 + 8];
        const float4 k3 = *(const float4*)&sK[l][dq * 16 + 12];
        s[0]  = fmaf(k0.x, vv, s[0]);  s[1]  = fmaf(k0.y, vv, s[1]);
        s[2]  = fmaf(k0.z, vv, s[2]);  s[3]  = fmaf(k0.w, vv, s[3]);
        s[4]  = fmaf(k1.x, vv, s[4]);  s[5]  = fmaf(k1.y, vv, s[5]);
        s[6]  = fmaf(k1.z, vv, s[6]);  s[7]  = fmaf(k1.w, vv, s[7]);
        s[8]  = fmaf(k2.x, vv, s[8]);  s[9]  = fmaf(k2.y, vv, s[9]);
        s[10] = fmaf(k2.z, vv, s[10]); s[11] = fmaf(k2.w, vv, s[11]);
        s[12] = fmaf(k3.x, vv, s[12]); s[13] = fmaf(k3.y, vv, s[13]);
        s[14] = fmaf(k3.z, vv, s[14]); s[15] = fmaf(k3.w, vv, s[15]);
    }
    const size_t sb = (((size_t)(n * NHEAD + h)) * NCHUNK + c) * 4096;
    #pragma unroll
    for (int i = 0; i < 16; ++i) S[sb + (size_t)(dq * 16 + i) * 64 + e] = s[i];

    float kp = 0.f;
    #pragma unroll
    for (int i = 0; i < 16; ++i) kp += sK[dq * 16 + i][e];
    part[dq][e] = kp;
    __syncthreads();
    if (tid < 64)
        ks[(((size_t)(n * NHEAD + h)) * NCHUNK + c) * 64 + tid] =
            part[0][tid] + part[1][tid] + part[2][tid] + part[3][tid];
}

// Kernel 2: O = Q@S_pre + tril(Q@K^T)@V. Prefix S_pre is summed inline from
// the raw chunk states of chunks < c (exclusive). Grid (16,8,2).
__global__ __launch_bounds__(256) void attn_out(
    const float* __restrict__ QKV, const float* __restrict__ S,
    const float* __restrict__ ks, bf16* __restrict__ O)
{
    const int c = blockIdx.x, h = blockIdx.y, n = blockIdx.z;
    const int tid = threadIdx.x;
    __shared__ float sQt[64][64];
    __shared__ float sKt[64][64];
    __shared__ float sV [64][64];
    __shared__ float sS [64][64];
    __shared__ float sPt[64][65];
    __shared__ float skp[64];

    const size_t nhS = ((size_t)(n * NHEAD + h)) * NCHUNK * 4096;
    const size_t nhK = ((size_t)(n * NHEAD + h)) * NCHUNK * 64;

    // inline exclusive prefix of chunk states
    {
        float4 aS[4] = {};
        for (int cc = 0; cc < c; ++cc) {
            const float* Sc = S + nhS + (size_t)cc * 4096;
            #pragma unroll
            for (int i = 0; i < 4; ++i) {
                const float4 t = *(const float4*)(Sc + i * 1024 + tid * 4);
                aS[i].x += t.x; aS[i].y += t.y; aS[i].z += t.z; aS[i].w += t.w;
            }
        }
        float* sSf = &sS[0][0];
        #pragma unroll
        for (int i = 0; i < 4; ++i)
            *(float4*)(sSf + i * 1024 + tid * 4) = aS[i];
        if (tid < 64) {
            float kp = 0.f;
            for (int cc = 0; cc < c; ++cc) kp += ks[nhK + cc * 64 + tid];
            skp[tid] = kp;
        }
    }

    const int lr = tid >> 4;
    const int c4 = (tid & 15) * 4;
    #pragma unroll
    for (int it = 0; it < 4; ++it) {
        const int row = it * 16 + lr;
        const size_t gb = ((size_t)(n * LSEQ + c * 64 + row)) * QS + h * DKH + c4;
        const float4 q4 = *(const float4*)(QKV + gb);
        const float4 k4 = *(const float4*)(QKV + gb + 512);
        const float4 v4 = *(const float4*)(QKV + gb + 1024);
        sQt[c4 + 0][row] = q4.x; sQt[c4 + 1][row] = q4.y;
        sQt[c4 + 2][row] = q4.z; sQt[c4 + 3][row] = q4.w;
        sKt[c4 + 0][row] = k4.x; sKt[c4 + 1][row] = k4.y;
        sKt[c4 + 2][row] = k4.z; sKt[c4 + 3][row] = k4.w;
        *(float4*)&sV[row][c4] = v4;
    }
    __syncthreads();

    const int m4 = (tid & 15) * 4;
    const int lg = tid >> 4;
    {
        float p[4][4] = {};
        for (int d = 0; d < 64; ++d) {
            const float4 k4 = *(const float4*)&sKt[d][m4];
            const float4 q4 = *(const float4*)&sQt[d][lg * 4];
            p[0][0] = fmaf(q4.x, k4.x, p[0][0]); p[0][1] = fmaf(q4.x, k4.y, p[0][1]);
            p[0][2] = fmaf(q4.x, k4.z, p[0][2]); p[0][3] = fmaf(q4.x, k4.w, p[0][3]);
            p[1][0] = fmaf(q4.y, k4.x, p[1][0]); p[1][1] = fmaf(q4.y, k4.y, p[1][1]);
            p[1][2] = fmaf(q4.y, k4.z, p[1][2]); p[1][3] = fmaf(q4.y, k4.w, p[1][3]);
            p[2][0] = fmaf(q4.z, k4.x, p[2][0]); p[2][1] = fmaf(q4.z, k4.y, p[2][1]);
            p[2][2] = fmaf(q4.z, k4.z, p[2][2]); p[2][3] = fmaf(q4.z, k4.w, p[2][3]);
            p[3][0] = fmaf(q4.w, k4.x, p[3][0]); p[3][1] = fmaf(q4.w, k4.y, p[3][1]);
            p[3][2] = fmaf(q4.w, k4.z, p[3][2]); p[3][3] = fmaf(q4.w, k4.w, p[3][3]);
        }
        #pragma unroll
        for (int jj = 0; jj < 4; ++jj)
            #pragma unroll
            for (int j = 0; j < 4; ++j)
                sPt[m4 + jj][lg * 4 + j] = p[j][jj];
    }
    __syncthreads();

    float acc[4][4] = {};
    float z[4] = {};
    const int lmax = lg * 4 + 3;
    for (int m = 0; m <= lmax; ++m) {
        const float4 v4 = *(const float4*)&sV[m][m4];
        #pragma unroll
        for (int j = 0; j < 4; ++j) {
            const int l = lg * 4 + j;
            float p = sPt[m][l];
            p = (m <= l) ? p : 0.f;
            z[j] += p;
            acc[j][0] = fmaf(p, v4.x, acc[j][0]);
            acc[j][1] = fmaf(p, v4.y, acc[j][1]);
            acc[j][2] = fmaf(p, v4.z, acc[j][2]);
            acc[j][3] = fmaf(p, v4.w, acc[j][3]);
        }
    }
    for (int d = 0; d < 64; ++d) {
        const float4 s4 = *(const float4*)&sS[d][m4];
        const float4 q4 = *(const float4*)&sQt[d][lg * 4];
        const float kp = skp[d];
        z[0] = fmaf(q4.x, kp, z[0]); z[1] = fmaf(q4.y, kp, z[1]);
        z[2] = fmaf(q4.z, kp, z[2]); z[3] = fmaf(q4.w, kp, z[3]);
        acc[0][0] = fmaf(q4.x, s4.x, acc[0][0]); acc[0][1] = fmaf(q4.x, s4.y, acc[0][1]);
        acc[0][2] = fmaf(q4.x, s4.z, acc[0][2]); acc[0][3] = fmaf(q4.x, s4.w, acc[0][3]);
        acc[1][0] = fmaf(q4.y, s4.x, acc[1][0]); acc[1][1] = fmaf(q4.y, s4.y, acc[1][1]);
        acc[1][2] = fmaf(q4.y, s4.z, acc[1][2]); acc[1][3] = fmaf(q4.y, s4.w, acc[1][3]);
        acc[2][0] = fmaf(q4.z, s4.x, acc[2][0]); acc[2][1] = fmaf(q4.z, s4.y, acc[2][1]);
        acc[2][2] = fmaf(q4.z, s4.z, acc[2][2]); acc[2][3] = fmaf(q4.z, s4.w, acc[2][3]);
        acc[3][0] = fmaf(q4.w, s4.x, acc[3][0]); acc[3][1] = fmaf(q4.w, s4.y, acc[3][1]);
        acc[3][2] = fmaf(q4.w, s4.z, acc[3][2]); acc[3][3] = fmaf(q4.w, s4.w, acc[3][3]);
    }
    #pragma unroll
    for (int j = 0; j < 4; ++j) {
        const int l = lg * 4 + j;
        const float rz = 1.f / (z[j] + 1e-6f);
        const size_t ob = ((size_t)(n * LSEQ + c * 64 + l)) * DM + h * DKH + m4;
        O[ob + 0] = __float2bfloat16(acc[j][0] * rz);
        O[ob + 1] = __float2bfloat16(acc[j][1] * rz);
        O[ob + 2] = __float2bfloat16(acc[j][2] * rz);
        O[ob + 3] = __float2bfloat16(acc[j][3] * rz);
    }
}

// ---------------------------------------------------------------------------
extern "C" void kernel_launch(void* const* d_in, const int* in_sizes, int n_in,
                              void* d_out, int out_size, void* d_ws, size_t ws_size,
                              hipStream_t stream)
{
    const float* x_img   = (const float*)d_in[0];
    const int*   x_txt   = (const int*)  d_in[1];
    const float* mask_i  = (const float*)d_in[2];
    const float* mask_t  = (const float*)d_in[3];
    const float* pos_r   = (const float*)d_in[4];
    const float* pos_c   = (const float*)d_in[5];
    const float* pos_t   = (const float*)d_in[6];
    const float* W_ei    = (const float*)d_in[7];
    const float* b_ei    = (const float*)d_in[8];
    const float* emb_txt = (const float*)d_in[9];
    const float* Wq      = (const float*)d_in[10];
    const float* bq      = (const float*)d_in[11];
    const float* Wk      = (const float*)d_in[12];
    const float* bk      = (const float*)d_in[13];
    const float* Wv      = (const float*)d_in[14];
    const float* bv      = (const float*)d_in[15];
    const float* Wo      = (const float*)d_in[16];
    const float* bo      = (const float*)d_in[17];
    const float* W1      = (const float*)d_in[18];
    const float* b1      = (const float*)d_in[19];
    const float* W2      = (const float*)d_in[20];
    const float* b2      = (const float*)d_in[21];
    const float* ln1_s   = (const float*)d_in[22];
    const float* ln1_b   = (const float*)d_in[23];
    const float* ln2_s   = (const float*)d_in[24];
    const float* ln2_b   = (const float*)d_in[25];
    const float* W_pi    = (const float*)d_in[26];
    const float* b_pi    = (const float*)d_in[27];
    const float* W_pt    = (const float*)d_in[28];
    const float* b_pt    = (const float*)d_in[29];

    float* ws = (float*)d_ws;
    size_t off = 0;
    auto alloc = [&](size_t nfloats) { float* p = ws + off; off += nfloats; return p; };

    float* Xb   = alloc(1048576);           // activations fp32 (N,L,D)
    float* Pb   = alloc(4194304);           // split-K partials / embed scratch
    float* QKVb = alloc(3145728);           // fused QKV fp32 (N,L,1536)
    float* Sb   = alloc(1048576);           // raw chunk KV sums
    float* ksb  = alloc(16384);
    float* qkvB = alloc(4 * QS);            // fused QKV bias
    float* hb   = alloc(8704);              // concat head bias
    bf16* Xh    = (bf16*)alloc(524288);     // activations bf16
    bf16* Ob    = (bf16*)alloc(524288);     // attention out bf16
    bf16* Tb    = (bf16*)alloc(2097152);    // FF intermediate bf16 (N,L,FF)
    bf16* ximgh = (bf16*)alloc(524288);
    bf16* QKVt  = (bf16*)alloc(1572864);    // (NL,1536,512)
    bf16* Wot   = (bf16*)alloc(524288);     // (NL,512,512)
    bf16* W1t   = (bf16*)alloc(2097152);    // (NL,2048,512)
    bf16* W2t   = (bf16*)alloc(2097152);    // (NL,512,2048)
    bf16* Weit  = (bf16*)alloc(131072);     // (512,512)
    bf16* Whead = (bf16*)alloc(2195456);    // (8576,512)

    const dim3 blk(256);
    const dim3 wblk(64);
    const dim3 gAttn(NCHUNK, NHEAD, NB);

    // ---- one setup dispatch: all casts + biases ----
    setup_all<<<dim3(CO_END), blk, 0, stream>>>(
        Wq, Wk, Wv, Wo, W1, W2, W_ei, W_pi, W_pt,
        QKVt, Wot, W1t, W2t, Weit, Whead,
        x_img, ximgh, bq, bk, bv, qkvB, b_pi, b_pt, hb);

    // ---- embedding ----
    wgemm32<<<dim3(16, 64), wblk, 0, stream>>>(
        ximgh, Weit, b_ei, Pb, nullptr, NROWS, 512, 512, OP_NONE, 512);
    embed_k<<<NROWS, blk, 0, stream>>>(Pb, x_txt, emb_txt, mask_i, mask_t,
                                       pos_r, pos_c, pos_t, Xb, Xh);

    for (int i = 0; i < NLAYER; ++i) {
        // fused QKV projection (elu+1 on Q,K cols): 3072 waves
        wgemm32<<<dim3(48, 64), wblk, 0, stream>>>(
            Xh, QKVt + (size_t)i * 786432, qkvB + i * QS,
            QKVb, nullptr, NROWS, 512, QS, OP_QKV, 512);

        attn_kv<<<gAttn, blk, 0, stream>>>(QKVb + 512, QKVb + 1024, Sb, ksb);
        attn_out<<<gAttn, blk, 0, stream>>>(QKVb, Sb, ksb, Ob);

        // out proj (split-K=2 partials): 2048 waves -> fused reduce+res+LN1
        wgemm32<<<dim3(16, 64, 2), wblk, 0, stream>>>(
            Ob, Wot + (size_t)i * 262144, nullptr,
            Pb, nullptr, NROWS, 512, 512, OP_PART, 256);
        ln_red<<<NROWS, blk, 0, stream>>>(Pb, 2, bo + (size_t)i * DM, Xb,
                                          ln1_s + (size_t)i * DM,
                                          ln1_b + (size_t)i * DM, Xb, Xh);

        // FF1 (gelu fused): 4096 waves -> FF2 (split-K=4): 4096 waves -> LN2
        wgemm32<<<dim3(64, 64), wblk, 0, stream>>>(
            Xh, W1t + (size_t)i * 1048576, b1 + (size_t)i * FFD,
            nullptr, Tb, NROWS, 512, FFD, OP_GELU, 512);
        wgemm32<<<dim3(16, 64, 4), wblk, 0, stream>>>(
            Tb, W2t + (size_t)i * 1048576, nullptr,
            Pb, nullptr, NROWS, 2048, 512, OP_PART, 512);
        ln_red<<<NROWS, blk, 0, stream>>>(Pb, 4, b2 + (size_t)i * DM, Xb,
                                          ln2_s + (size_t)i * DM,
                                          ln2_b + (size_t)i * DM, Xb, Xh);
    }

    // ---- merged heads: best-measured 4-wave 128x128 2-stage + XCD swizzle ----
    float* out = (float*)d_out;
    gemm16<128, 128><<<dim3(16, 67), blk, 0, stream>>>(
        Xh, Whead, hb, out, out + 1048576, NROWS, 512, NHEADCAT, 512);
}

// Round 6
// 609.227 us; speedup vs baseline: 1.1064x; 1.0538x over previous
//
#include <hip/hip_runtime.h>
#include <hip/hip_bf16.h>
#include <math.h>

// Model dims
#define NB 2
#define LSEQ 1024
#define DM 512
#define FFD 2048
#define NHEAD 8
#define DKH 64
#define NLAYER 4
#define VOCAB 8000
#define NCHUNK 16           // L / 64
#define NROWS (NB * LSEQ)   // 2048
#define QS 1536             // fused QKV row stride
#define NHEADCAT 8512       // 512 (img) + 8000 (txt)
#define NHEADPAD 8576       // padded: 512 + 252*32

#define OP_NONE 0
#define OP_GELU 2
#define OP_PART 4   // raw fp32 partial at outF + z*M*Nout (split-K)
#define OP_HEAD 5   // col<512 -> outF (img), else outF2 (txt); grid x=M-tiles!

typedef __attribute__((ext_vector_type(8))) short short8;
typedef __attribute__((ext_vector_type(4))) float f32x4;
typedef __hip_bfloat16 bf16;

// ---------------------------------------------------------------------------
// 32x32 transpose-cast tile: src (K,N) fp32 -> dst (Npad,K) bf16; n>=N -> 0.
// Vectorized: float4 loads (16B/lane), 8B stores.
// ---------------------------------------------------------------------------
__device__ __forceinline__ void cast_tile(
    const float* __restrict__ s, bf16* __restrict__ d, int K, int N,
    int n0, int k0, int tid)
{
    __shared__ float tile[32][33];
    const int r  = tid >> 3;          // k within tile, 0..31
    const int c4 = (tid & 7) * 4;     // n within tile, multiple of 4
    const int n  = n0 + c4;
    float4 v = make_float4(0.f, 0.f, 0.f, 0.f);
    if (n < N)                        // N % 4 == 0, so whole float4 in or out
        v = *(const float4*)(s + (size_t)(k0 + r) * N + n);
    tile[r][c4 + 0] = v.x; tile[r][c4 + 1] = v.y;
    tile[r][c4 + 2] = v.z; tile[r][c4 + 3] = v.w;
    __syncthreads();
    const int nr = tid >> 3;          // n-row for write
    const int kc = (tid & 7) * 4;     // k cols, multiple of 4
    bf16 o[4];
    o[0] = __float2bfloat16(tile[kc + 0][nr]);
    o[1] = __float2bfloat16(tile[kc + 1][nr]);
    o[2] = __float2bfloat16(tile[kc + 2][nr]);
    o[3] = __float2bfloat16(tile[kc + 3][nr]);
    *(unsigned long long*)(d + (size_t)(n0 + nr) * K + k0 + kc) =
        *(const unsigned long long*)o;
    __syncthreads();
}

// ---------------------------------------------------------------------------
// ONE setup dispatch: all weight transposes-casts, x_img cast, bias prep.
// QKV weights now stored PER-HEAD-GROUPED: B-row index = h*192 + which*64 +
// (col&63)  ->  a (chunk,head) GEMM block sees [Q_h|K_h|V_h] as 192
// contiguous rows (enables the fused qkv_attn kernel).
// ---------------------------------------------------------------------------
#define CO_QKVO 0        // 4096: Wq/Wk/Wv/Wo (4 layers x 4 x 256 tiles)
#define CO_W1   4096     // 4096
#define CO_W2   8192     // 4096
#define CO_WEI  12288    // 256
#define CO_WPI  12544    // 256
#define CO_WPT  12800    // 4032
#define CO_XIMG 16832    // 1024
#define CO_QKVB 17856    // 4
#define CO_HB   17860    // 34
#define CO_END  17894

__global__ __launch_bounds__(256) void setup_all(
    const float* __restrict__ Wq, const float* __restrict__ Wk,
    const float* __restrict__ Wv, const float* __restrict__ Wo,
    const float* __restrict__ W1, const float* __restrict__ W2,
    const float* __restrict__ Wei, const float* __restrict__ Wpi,
    const float* __restrict__ Wpt,
    bf16* __restrict__ QKVt, bf16* __restrict__ Wot,
    bf16* __restrict__ W1t, bf16* __restrict__ W2t,
    bf16* __restrict__ Weit, bf16* __restrict__ Whead,
    const float* __restrict__ x_img, bf16* __restrict__ ximgh,
    const float* __restrict__ bq, const float* __restrict__ bk,
    const float* __restrict__ bv, float* __restrict__ qkvB,
    const float* __restrict__ bpi, const float* __restrict__ bpt,
    float* __restrict__ hb)
{
    const int id = blockIdx.x;
    const int tid = threadIdx.x;

    if (id < CO_W1) {                       // QKVO 512x512 casts
        const int rel = id;
        const int z = rel >> 8, t = rel & 255;
        const int layer = z >> 2, which = z & 3;
        const float* src = (which == 0 ? Wq : which == 1 ? Wk : which == 2 ? Wv : Wo)
                           + (size_t)layer * 262144;
        const int n0 = (t & 15) * 32, k0 = (t >> 4) * 32;
        if (which < 3) {
            // per-head-grouped row remap: row = h*192 + which*64 + (n&63)
            //   = h*128 + which*64 + n  (h = n>>6)
            const int h = n0 >> 6;
            bf16* dst = QKVt + (size_t)layer * 786432
                      + (size_t)(h * 128 + which * 64) * 512;
            cast_tile(src, dst, 512, 512, n0, k0, tid);
        } else {
            cast_tile(src, Wot + (size_t)layer * 262144, 512, 512, n0, k0, tid);
        }
    } else if (id < CO_W2) {                // W1 (512,2048) x4
        const int rel = id - CO_W1;
        const int z = rel >> 10, t = rel & 1023;
        cast_tile(W1 + (size_t)z * 1048576, W1t + (size_t)z * 1048576,
                  512, 2048, (t & 63) * 32, (t >> 6) * 32, tid);
    } else if (id < CO_WEI) {               // W2 (2048,512) x4
        const int rel = id - CO_W2;
        const int z = rel >> 10, t = rel & 1023;
        cast_tile(W2 + (size_t)z * 1048576, W2t + (size_t)z * 1048576,
                  2048, 512, (t & 15) * 32, (t >> 4) * 32, tid);
    } else if (id < CO_WPI) {               // W_ei
        const int t = id - CO_WEI;
        cast_tile(Wei, Weit, 512, 512, (t & 15) * 32, (t >> 4) * 32, tid);
    } else if (id < CO_WPT) {               // W_pi -> Whead rows 0..511
        const int t = id - CO_WPI;
        cast_tile(Wpi, Whead, 512, 512, (t & 15) * 32, (t >> 4) * 32, tid);
    } else if (id < CO_XIMG) {              // W_pt -> Whead rows 512..8575
        const int t = id - CO_WPT;
        cast_tile(Wpt, Whead + 262144, 512, VOCAB,
                  (t % 252) * 32, (t / 252) * 32, tid);
    } else if (id < CO_QKVB) {              // x_img elementwise cast
        const int i = (id - CO_XIMG) * 256 + tid;   // i < 262144 (x4 floats)
        const float4 v = *(const float4*)(x_img + (size_t)i * 4);
        ximgh[(size_t)i * 4 + 0] = __float2bfloat16(v.x);
        ximgh[(size_t)i * 4 + 1] = __float2bfloat16(v.y);
        ximgh[(size_t)i * 4 + 2] = __float2bfloat16(v.z);
        ximgh[(size_t)i * 4 + 3] = __float2bfloat16(v.w);
    } else if (id < CO_HB) {                // per-head QKV bias: [bq_h|bk_h|bv_h]
        const int z = id - CO_QKVB;
        for (int j = tid; j < QS; j += 256) {
            const int h = j / 192, rem = j - h * 192;
            const int which = rem >> 6, idx = rem & 63;
            const float* bsrc = (which == 0 ? bq : which == 1 ? bk : bv);
            qkvB[z * QS + j] = bsrc[z * DM + h * 64 + idx];
        }
    } else {                                // concat head bias
        const int j = (id - CO_HB) * 256 + tid;
        if (j < NHEADPAD)
            hb[j] = (j < 512) ? bpi[j] : (j < NHEADCAT ? bpt[j - 512] : 0.f);
    }
}

// ---------------------------------------------------------------------------
// bf16 MFMA GEMM (round-2 proven config = session best): 4 waves, 2-stage
// double-buffer, counted vmcnt, raw s_barrier.
// OP_HEAD: transposed grid (x = M-tiles) + bijective XCD-chunked swizzle.
// ---------------------------------------------------------------------------
template<int BM, int BN>
__global__ __launch_bounds__(256) void gemm16(
    const bf16* __restrict__ A, const bf16* __restrict__ Bt,
    const float* __restrict__ bias,
    float* __restrict__ outF, float* __restrict__ outF2,
    bf16* __restrict__ outH,
    int M, int K, int Nout, int op, int kslab)
{
    constexpr int WM = BM / 2, WN = BN / 2, MI = WM / 16, NI = WN / 16;
    constexpr int LA = BM / 64, LB = BN / 64;
    constexpr int NL = LA + LB;
    __shared__ bf16 As[2][BM * 32];
    __shared__ bf16 Bs[2][BN * 32];
    const int tid = threadIdx.x;
    const int lane = tid & 63;
    const int wave = tid >> 6;
    const int wm = (wave >> 1) * WM, wn = (wave & 1) * WN;

    int bxi = blockIdx.x, byi = blockIdx.y;
    if (op == OP_HEAD) {
        const int gx = gridDim.x;
        const int nwg = gx * gridDim.y;
        int flat = byi * gx + bxi;
        const int q = nwg >> 3, r = nwg & 7;
        const int xcd = flat & 7, lid = flat >> 3;
        flat = (xcd < r ? xcd * (q + 1) : r * (q + 1) + (xcd - r) * q) + lid;
        bxi = flat % gx;
        byi = flat / gx;
    }
    const int bm = (op == OP_HEAD ? bxi : blockIdx.y) * BM;
    const int bn = (op == OP_HEAD ? byi : blockIdx.x) * BN;
    const int l16 = lane & 15, quad = lane >> 4;

    const int rA = tid >> 2;
    const int c8 = (tid & 3) << 3;

    f32x4 acc[MI][NI];
    #pragma unroll
    for (int i = 0; i < MI; ++i)
        #pragma unroll
        for (int j = 0; j < NI; ++j) acc[i][j] = (f32x4){0.f, 0.f, 0.f, 0.f};

    const bf16* gA = A  + (size_t)(bm + rA) * K + c8;
    const bf16* gB = Bt + (size_t)(bn + rA) * K + c8;
    const int ldsWaveOff = wave * 1024;

    const int kStart = blockIdx.z * kslab;
    const int kEnd = kStart + kslab;

    auto stage = [&](int buf, int k0) {
        #pragma unroll
        for (int i = 0; i < LA; ++i)
            __builtin_amdgcn_global_load_lds(
                (const __attribute__((address_space(1))) void*)(gA + (size_t)i * 64 * K + k0),
                (__attribute__((address_space(3))) void*)((char*)As[buf] + i * 4096 + ldsWaveOff),
                16, 0, 0);
        #pragma unroll
        for (int i = 0; i < LB; ++i)
            __builtin_amdgcn_global_load_lds(
                (const __attribute__((address_space(1))) void*)(gB + (size_t)i * 64 * K + k0),
                (__attribute__((address_space(3))) void*)((char*)Bs[buf] + i * 4096 + ldsWaveOff),
                16, 0, 0);
    };

    stage(0, kStart);
    int cur = 0;
    for (int k0 = kStart; k0 < kEnd; k0 += 32) {
        const bool hasNext = (k0 + 32 < kEnd);
        if (hasNext) {
            stage(cur ^ 1, k0 + 32);
            asm volatile("s_waitcnt vmcnt(%0)" :: "n"(NL) : "memory");
        } else {
            asm volatile("s_waitcnt vmcnt(0)" ::: "memory");
        }
        __builtin_amdgcn_s_barrier();
        short8 a[MI], b[NI];
        #pragma unroll
        for (int i = 0; i < MI; ++i)
            a[i] = *(const short8*)(As[cur] + (size_t)(wm + i * 16 + l16) * 32 + quad * 8);
        #pragma unroll
        for (int j = 0; j < NI; ++j)
            b[j] = *(const short8*)(Bs[cur] + (size_t)(wn + j * 16 + l16) * 32 + quad * 8);
        #pragma unroll
        for (int i = 0; i < MI; ++i)
            #pragma unroll
            for (int j = 0; j < NI; ++j)
                acc[i][j] = __builtin_amdgcn_mfma_f32_16x16x32_bf16(
                    a[i], b[j], acc[i][j], 0, 0, 0);
        __builtin_amdgcn_s_barrier();
        cur ^= 1;
    }

    if (op == OP_PART) {
        float* dst = outF + (size_t)blockIdx.z * (size_t)M * Nout;
        #pragma unroll
        for (int j = 0; j < NI; ++j) {
            const int col = bn + wn + j * 16 + l16;
            #pragma unroll
            for (int i = 0; i < MI; ++i)
                #pragma unroll
                for (int r = 0; r < 4; ++r) {
                    const int row = bm + wm + i * 16 + quad * 4 + r;
                    dst[(size_t)row * Nout + col] = acc[i][j][r];
                }
        }
        return;
    }
    if (op == OP_HEAD) {
        #pragma unroll
        for (int j = 0; j < NI; ++j) {
            const int col = bn + wn + j * 16 + l16;
            const bool cok = (col < NHEADCAT);
            const float bz = cok ? bias[col] : 0.f;
            #pragma unroll
            for (int i = 0; i < MI; ++i)
                #pragma unroll
                for (int r = 0; r < 4; ++r) {
                    const int row = bm + wm + i * 16 + quad * 4 + r;
                    const float v = acc[i][j][r] + bz;
                    if (cok) {
                        if (col < 512) outF[(size_t)row * 512 + col] = v;
                        else           outF2[(size_t)row * VOCAB + (col - 512)] = v;
                    }
                }
        }
        return;
    }

    #pragma unroll
    for (int j = 0; j < NI; ++j) {
        const int col = bn + wn + j * 16 + l16;
        const bool cok = (col < Nout);
        const float bz = cok ? bias[col] : 0.f;
        #pragma unroll
        for (int i = 0; i < MI; ++i) {
            #pragma unroll
            for (int r = 0; r < 4; ++r) {
                const int row = bm + wm + i * 16 + quad * 4 + r;
                float v = acc[i][j][r] + bz;
                if (op == OP_GELU) v = 0.5f * v * (1.f + erff(v * 0.70710678118654752f));
                if (cok) {
                    if (outF) outF[(size_t)row * Nout + col] = v;
                    if (outH) outH[(size_t)row * Nout + col] = __float2bfloat16(v);
                }
            }
        }
    }
}

// ---------------------------------------------------------------------------
// FUSED QKV projection + attn chunk-state kernel. Grid (NCHUNK, NHEAD, NB).
// Block = one (chunk c, head h): 64 rows x 192 cols [Q_h|K_h|V_h] GEMM
// (per-head-grouped weights), then — since K_c,V_c are on-chip — the
// attn_kv reduction (S_c = K_c^T V_c, ksum_c) runs in the epilogue.
// Eliminates the attn_kv dispatch + its 8.4MB/layer QKV re-read.
// K-loop: proven round-2 2-stage counted-vmcnt structure.
// ---------------------------------------------------------------------------
__global__ __launch_bounds__(256) void qkv_attn(
    const bf16* __restrict__ A, const bf16* __restrict__ Bt,
    const float* __restrict__ bias,
    float* __restrict__ QKVb, float* __restrict__ S, float* __restrict__ ks)
{
    // LDS plan: [0,8K) As[2][64*32] bf16 | [8K,32K) Bs[2][192*32] bf16
    // overlay after K-loop: [0,16K) sK f32[64][64] | [16K,32K) sV | [32K,33K) part
    __shared__ char smem[33792];
    const int c = blockIdx.x, h = blockIdx.y, n = blockIdx.z;
    const int tid = threadIdx.x;
    const int lane = tid & 63;
    const int wave = tid >> 6;
    const int l16 = lane & 15, quad = lane >> 4;
    const int r0 = n * LSEQ + c * 64;
    const int wn = wave * 48;                 // wave's 48-col slice of 192

    const bf16* Bh = Bt + (size_t)(h * 192) * 512;
    const float* bh = bias + h * 192;

    f32x4 acc[4][3];
    #pragma unroll
    for (int i = 0; i < 4; ++i)
        #pragma unroll
        for (int j = 0; j < 3; ++j) acc[i][j] = (f32x4){0.f, 0.f, 0.f, 0.f};

    const bf16* gA = A + (size_t)(r0 + (tid >> 2)) * 512 + ((tid & 3) << 3);
    const int ldsWaveOff = wave * 1024;

    auto stage = [&](int buf, int k0) {
        __builtin_amdgcn_global_load_lds(
            (const __attribute__((address_space(1))) void*)(gA + k0),
            (__attribute__((address_space(3))) void*)(smem + buf * 4096 + ldsWaveOff),
            16, 0, 0);
        #pragma unroll
        for (int p = 0; p < 3; ++p)
            __builtin_amdgcn_global_load_lds(
                (const __attribute__((address_space(1))) void*)(
                    Bh + (size_t)(p * 64 + (tid >> 2)) * 512 + ((tid & 3) << 3) + k0),
                (__attribute__((address_space(3))) void*)(
                    smem + 8192 + buf * 12288 + p * 4096 + ldsWaveOff),
                16, 0, 0);
    };

    stage(0, 0);
    int cur = 0;
    for (int k0 = 0; k0 < 512; k0 += 32) {
        if (k0 + 32 < 512) {
            stage(cur ^ 1, k0 + 32);
            asm volatile("s_waitcnt vmcnt(4)" ::: "memory");
        } else {
            asm volatile("s_waitcnt vmcnt(0)" ::: "memory");
        }
        __builtin_amdgcn_s_barrier();
        const bf16* Asb = (const bf16*)(smem + cur * 4096);
        const bf16* Bsb = (const bf16*)(smem + 8192 + cur * 12288);
        short8 a[4], b[3];
        #pragma unroll
        for (int i = 0; i < 4; ++i)
            a[i] = *(const short8*)(Asb + (i * 16 + l16) * 32 + quad * 8);
        #pragma unroll
        for (int j = 0; j < 3; ++j)
            b[j] = *(const short8*)(Bsb + (wn + j * 16 + l16) * 32 + quad * 8);
        #pragma unroll
        for (int i = 0; i < 4; ++i)
            #pragma unroll
            for (int j = 0; j < 3; ++j)
                acc[i][j] = __builtin_amdgcn_mfma_f32_16x16x32_bf16(
                    a[i], b[j], acc[i][j], 0, 0, 0);
        __builtin_amdgcn_s_barrier();
        cur ^= 1;
    }
    __syncthreads();                          // LDS reuse boundary

    float* sK   = (float*)smem;               // [64][64]
    float* sV   = (float*)(smem + 16384);     // [64][64]
    float* part = (float*)(smem + 32768);     // [4][64]

    // epilogue: bias + elu+1 (Q,K) -> global QKVb; stash K,V into LDS
    #pragma unroll
    for (int j = 0; j < 3; ++j) {
        const int col = wn + j * 16 + l16;    // 0..191
        const float bz = bh[col];
        int gcol;
        if (col < 64)        gcol = h * 64 + col;
        else if (col < 128)  gcol = 512 + h * 64 + (col - 64);
        else                 gcol = 1024 + h * 64 + (col - 128);
        #pragma unroll
        for (int i = 0; i < 4; ++i)
            #pragma unroll
            for (int r = 0; r < 4; ++r) {
                const int row = i * 16 + quad * 4 + r;
                float v = acc[i][j][r] + bz;
                if (col < 128) v = (v > 0.f) ? v + 1.f : expf(v);
                QKVb[(size_t)(r0 + row) * QS + gcol] = v;
                if (col >= 128)     sV[row * 64 + (col - 128)] = v;
                else if (col >= 64) sK[row * 64 + (col - 64)]  = v;
            }
    }
    __syncthreads();

    // attn_kv reduction (ported verbatim): S_c = K^T V, ksum
    const int e = tid & 63, dq = tid >> 6;
    float s[16] = {};
    for (int l = 0; l < 64; ++l) {
        const float vv = sV[l * 64 + e];
        const float4 k0v = *(const float4*)(sK + l * 64 + dq * 16 + 0);
        const float4 k1v = *(const float4*)(sK + l * 64 + dq * 16 + 4);
        const float4 k2v = *(const float4*)(sK + l * 64 + dq * 16 + 8);
        const float4 k3v = *(const float4*)(sK + l * 64 + dq * 16 + 12);
        s[0]  = fmaf(k0v.x, vv, s[0]);  s[1]  = fmaf(k0v.y, vv, s[1]);
        s[2]  = fmaf(k0v.z, vv, s[2]);  s[3]  = fmaf(k0v.w, vv, s[3]);
        s[4]  = fmaf(k1v.x, vv, s[4]);  s[5]  = fmaf(k1v.y, vv, s[5]);
        s[6]  = fmaf(k1v.z, vv, s[6]);  s[7]  = fmaf(k1v.w, vv, s[7]);
        s[8]  = fmaf(k2v.x, vv, s[8]);  s[9]  = fmaf(k2v.y, vv, s[9]);
        s[10] = fmaf(k2v.z, vv, s[10]); s[11] = fmaf(k2v.w, vv, s[11]);
        s[12] = fmaf(k3v.x, vv, s[12]); s[13] = fmaf(k3v.y, vv, s[13]);
        s[14] = fmaf(k3v.z, vv, s[14]); s[15] = fmaf(k3v.w, vv, s[15]);
    }
    const size_t sb = (((size_t)(n * NHEAD + h)) * NCHUNK + c) * 4096;
    #pragma unroll
    for (int i = 0; i < 16; ++i) S[sb + (size_t)(dq * 16 + i) * 64 + e] = s[i];

    float kp = 0.f;
    #pragma unroll
    for (int i = 0; i < 16; ++i) kp += sK[(dq * 16 + i) * 64 + e];
    part[dq * 64 + e] = kp;
    __syncthreads();
    if (tid < 64)
        ks[(((size_t)(n * NHEAD + h)) * NCHUNK + c) * 64 + tid] =
            part[tid] + part[64 + tid] + part[128 + tid] + part[192 + tid];
}

// ---------------------------------------------------------------------------
// Embedding combine. gI = x_img @ W_ei + b_ei (precomputed fp32).
// ---------------------------------------------------------------------------
__global__ __launch_bounds__(256) void embed_k(
    const float* __restrict__ gI, const int* __restrict__ xt,
    const float* __restrict__ emb,
    const float* __restrict__ mi, const float* __restrict__ mt,
    const float* __restrict__ pr, const float* __restrict__ pc,
    const float* __restrict__ pt, float* __restrict__ X, bf16* __restrict__ Xh)
{
    const int row = blockIdx.x;
    const float prv = pr[row], pcv = pc[row], ptv = pt[row];
    const float miv = mi[row], mtv = mt[row];
    const int tok = xt[row];
    const float LOG1E4 = 9.2103403719761836f;
    const float LI127 = LOG1E4 / 127.f;
    const float LI255 = LOG1E4 / 255.f;

    for (int d = threadIdx.x; d < DM; d += 256) {
        float ip;
        if (d < 128)       ip = sinf(prv * expf(-(float)d * LI127));
        else if (d < 256)  ip = cosf(prv * expf(-(float)(d - 128) * LI127));
        else if (d < 384)  ip = sinf(pcv * expf(-(float)(d - 256) * LI127));
        else               ip = cosf(pcv * expf(-(float)(d - 384) * LI127));
        float tp;
        if (d < 256) tp = sinf(ptv * expf(-(float)d * LI255));
        else         tp = cosf(ptv * expf(-(float)(d - 256) * LI255));
        const float v = miv * (gI[(size_t)row * DM + d] + ip)
                      + mtv * (emb[(size_t)tok * DM + d] + tp);
        X[(size_t)row * DM + d] = v;
        Xh[(size_t)row * DM + d] = __float2bfloat16(v);
    }
}

// ---------------------------------------------------------------------------
// Fused partial-sum + bias + residual + LayerNorm (out may alias res).
// ---------------------------------------------------------------------------
__global__ __launch_bounds__(256) void ln_red(
    const float* __restrict__ P, int nP,
    const float* __restrict__ bias, const float* __restrict__ res,
    const float* __restrict__ g, const float* __restrict__ b,
    float* __restrict__ out, bf16* __restrict__ outh)
{
    const int row = blockIdx.x;
    const int tid = threadIdx.x;
    const int lane = tid & 63, wv = tid >> 6;
    const size_t base = (size_t)row * DM;
    float x0 = res[base + tid] + bias[tid];
    float x1 = res[base + tid + 256] + bias[tid + 256];
    for (int p = 0; p < nP; ++p) {
        x0 += P[(size_t)p * 1048576 + base + tid];
        x1 += P[(size_t)p * 1048576 + base + tid + 256];
    }
    __shared__ float redA[4];
    __shared__ float redB[4];
    float s = x0 + x1;
    #pragma unroll
    for (int off = 32; off > 0; off >>= 1) s += __shfl_down(s, off);
    if (lane == 0) redA[wv] = s;
    __syncthreads();
    const float mean = (redA[0] + redA[1] + redA[2] + redA[3]) * (1.f / (float)DM);
    const float d0 = x0 - mean, d1 = x1 - mean;
    float v = d0 * d0 + d1 * d1;
    #pragma unroll
    for (int off = 32; off > 0; off >>= 1) v += __shfl_down(v, off);
    if (lane == 0) redB[wv] = v;
    __syncthreads();
    const float var = (redB[0] + redB[1] + redB[2] + redB[3]) * (1.f / (float)DM);
    const float rstd = rsqrtf(var + 1e-5f);
    const float y0 = d0 * rstd * g[tid] + b[tid];
    const float y1 = d1 * rstd * g[tid + 256] + b[tid + 256];
    out[base + tid]        = y0;
    out[base + tid + 256]  = y1;
    outh[base + tid]       = __float2bfloat16(y0);
    outh[base + tid + 256] = __float2bfloat16(y1);
}

// ---------------------------------------------------------------------------
// attn_out: O = Q@S_pre + tril(Q@K^T)@V. Prefix S_pre summed inline from raw
// chunk states of chunks < c (exclusive). Grid (16,8,2). (Unchanged.)
// ---------------------------------------------------------------------------
__global__ __launch_bounds__(256) void attn_out(
    const float* __restrict__ QKV, const float* __restrict__ S,
    const float* __restrict__ ks, bf16* __restrict__ O)
{
    const int c = blockIdx.x, h = blockIdx.y, n = blockIdx.z;
    const int tid = threadIdx.x;
    __shared__ float sQt[64][64];
    __shared__ float sKt[64][64];
    __shared__ float sV [64][64];
    __shared__ float sS [64][64];
    __shared__ float sPt[64][65];
    __shared__ float skp[64];

    const size_t nhS = ((size_t)(n * NHEAD + h)) * NCHUNK * 4096;
    const size_t nhK = ((size_t)(n * NHEAD + h)) * NCHUNK * 64;

    {
        float4 aS[4] = {};
        for (int cc = 0; cc < c; ++cc) {
            const float* Sc = S + nhS + (size_t)cc * 4096;
            #pragma unroll
            for (int i = 0; i < 4; ++i) {
                const float4 t = *(const float4*)(Sc + i * 1024 + tid * 4);
                aS[i].x += t.x; aS[i].y += t.y; aS[i].z += t.z; aS[i].w += t.w;
            }
        }
        float* sSf = &sS[0][0];
        #pragma unroll
        for (int i = 0; i < 4; ++i)
            *(float4*)(sSf + i * 1024 + tid * 4) = aS[i];
        if (tid < 64) {
            float kp = 0.f;
            for (int cc = 0; cc < c; ++cc) kp += ks[nhK + cc * 64 + tid];
            skp[tid] = kp;
        }
    }

    const int lr = tid >> 4;
    const int c4 = (tid & 15) * 4;
    #pragma unroll
    for (int it = 0; it < 4; ++it) {
        const int row = it * 16 + lr;
        const size_t gb = ((size_t)(n * LSEQ + c * 64 + row)) * QS + h * DKH + c4;
        const float4 q4 = *(const float4*)(QKV + gb);
        const float4 k4 = *(const float4*)(QKV + gb + 512);
        const float4 v4 = *(const float4*)(QKV + gb + 1024);
        sQt[c4 + 0][row] = q4.x; sQt[c4 + 1][row] = q4.y;
        sQt[c4 + 2][row] = q4.z; sQt[c4 + 3][row] = q4.w;
        sKt[c4 + 0][row] = k4.x; sKt[c4 + 1][row] = k4.y;
        sKt[c4 + 2][row] = k4.z; sKt[c4 + 3][row] = k4.w;
        *(float4*)&sV[row][c4] = v4;
    }
    __syncthreads();

    const int m4 = (tid & 15) * 4;
    const int lg = tid >> 4;
    {
        float p[4][4] = {};
        for (int d = 0; d < 64; ++d) {
            const float4 k4 = *(const float4*)&sKt[d][m4];
            const float4 q4 = *(const float4*)&sQt[d][lg * 4];
            p[0][0] = fmaf(q4.x, k4.x, p[0][0]); p[0][1] = fmaf(q4.x, k4.y, p[0][1]);
            p[0][2] = fmaf(q4.x, k4.z, p[0][2]); p[0][3] = fmaf(q4.x, k4.w, p[0][3]);
            p[1][0] = fmaf(q4.y, k4.x, p[1][0]); p[1][1] = fmaf(q4.y, k4.y, p[1][1]);
            p[1][2] = fmaf(q4.y, k4.z, p[1][2]); p[1][3] = fmaf(q4.y, k4.w, p[1][3]);
            p[2][0] = fmaf(q4.z, k4.x, p[2][0]); p[2][1] = fmaf(q4.z, k4.y, p[2][1]);
            p[2][2] = fmaf(q4.z, k4.z, p[2][2]); p[2][3] = fmaf(q4.z, k4.w, p[2][3]);
            p[3][0] = fmaf(q4.w, k4.x, p[3][0]); p[3][1] = fmaf(q4.w, k4.y, p[3][1]);
            p[3][2] = fmaf(q4.w, k4.z, p[3][2]); p[3][3] = fmaf(q4.w, k4.w, p[3][3]);
        }
        #pragma unroll
        for (int jj = 0; jj < 4; ++jj)
            #pragma unroll
            for (int j = 0; j < 4; ++j)
                sPt[m4 + jj][lg * 4 + j] = p[j][jj];
    }
    __syncthreads();

    float acc[4][4] = {};
    float z[4] = {};
    const int lmax = lg * 4 + 3;
    for (int m = 0; m <= lmax; ++m) {
        const float4 v4 = *(const float4*)&sV[m][m4];
        #pragma unroll
        for (int j = 0; j < 4; ++j) {
            const int l = lg * 4 + j;
            float p = sPt[m][l];
            p = (m <= l) ? p : 0.f;
            z[j] += p;
            acc[j][0] = fmaf(p, v4.x, acc[j][0]);
            acc[j][1] = fmaf(p, v4.y, acc[j][1]);
            acc[j][2] = fmaf(p, v4.z, acc[j][2]);
            acc[j][3] = fmaf(p, v4.w, acc[j][3]);
        }
    }
    for (int d = 0; d < 64; ++d) {
        const float4 s4 = *(const float4*)&sS[d][m4];
        const float4 q4 = *(const float4*)&sQt[d][lg * 4];
        const float kp = skp[d];
        z[0] = fmaf(q4.x, kp, z[0]); z[1] = fmaf(q4.y, kp, z[1]);
        z[2] = fmaf(q4.z, kp, z[2]); z[3] = fmaf(q4.w, kp, z[3]);
        acc[0][0] = fmaf(q4.x, s4.x, acc[0][0]); acc[0][1] = fmaf(q4.x, s4.y, acc[0][1]);
        acc[0][2] = fmaf(q4.x, s4.z, acc[0][2]); acc[0][3] = fmaf(q4.x, s4.w, acc[0][3]);
        acc[1][0] = fmaf(q4.y, s4.x, acc[1][0]); acc[1][1] = fmaf(q4.y, s4.y, acc[1][1]);
        acc[1][2] = fmaf(q4.y, s4.z, acc[1][2]); acc[1][3] = fmaf(q4.y, s4.w, acc[1][3]);
        acc[2][0] = fmaf(q4.z, s4.x, acc[2][0]); acc[2][1] = fmaf(q4.z, s4.y, acc[2][1]);
        acc[2][2] = fmaf(q4.z, s4.z, acc[2][2]); acc[2][3] = fmaf(q4.z, s4.w, acc[2][3]);
        acc[3][0] = fmaf(q4.w, s4.x, acc[3][0]); acc[3][1] = fmaf(q4.w, s4.y, acc[3][1]);
        acc[3][2] = fmaf(q4.w, s4.z, acc[3][2]); acc[3][3] = fmaf(q4.w, s4.w, acc[3][3]);
    }
    #pragma unroll
    for (int j = 0; j < 4; ++j) {
        const int l = lg * 4 + j;
        const float rz = 1.f / (z[j] + 1e-6f);
        const size_t ob = ((size_t)(n * LSEQ + c * 64 + l)) * DM + h * DKH + m4;
        O[ob + 0] = __float2bfloat16(acc[j][0] * rz);
        O[ob + 1] = __float2bfloat16(acc[j][1] * rz);
        O[ob + 2] = __float2bfloat16(acc[j][2] * rz);
        O[ob + 3] = __float2bfloat16(acc[j][3] * rz);
    }
}

// ---------------------------------------------------------------------------
extern "C" void kernel_launch(void* const* d_in, const int* in_sizes, int n_in,
                              void* d_out, int out_size, void* d_ws, size_t ws_size,
                              hipStream_t stream)
{
    const float* x_img   = (const float*)d_in[0];
    const int*   x_txt   = (const int*)  d_in[1];
    const float* mask_i  = (const float*)d_in[2];
    const float* mask_t  = (const float*)d_in[3];
    const float* pos_r   = (const float*)d_in[4];
    const float* pos_c   = (const float*)d_in[5];
    const float* pos_t   = (const float*)d_in[6];
    const float* W_ei    = (const float*)d_in[7];
    const float* b_ei    = (const float*)d_in[8];
    const float* emb_txt = (const float*)d_in[9];
    const float* Wq      = (const float*)d_in[10];
    const float* bq      = (const float*)d_in[11];
    const float* Wk      = (const float*)d_in[12];
    const float* bk      = (const float*)d_in[13];
    const float* Wv      = (const float*)d_in[14];
    const float* bv      = (const float*)d_in[15];
    const float* Wo      = (const float*)d_in[16];
    const float* bo      = (const float*)d_in[17];
    const float* W1      = (const float*)d_in[18];
    const float* b1      = (const float*)d_in[19];
    const float* W2      = (const float*)d_in[20];
    const float* b2      = (const float*)d_in[21];
    const float* ln1_s   = (const float*)d_in[22];
    const float* ln1_b   = (const float*)d_in[23];
    const float* ln2_s   = (const float*)d_in[24];
    const float* ln2_b   = (const float*)d_in[25];
    const float* W_pi    = (const float*)d_in[26];
    const float* b_pi    = (const float*)d_in[27];
    const float* W_pt    = (const float*)d_in[28];
    const float* b_pt    = (const float*)d_in[29];

    float* ws = (float*)d_ws;
    size_t off = 0;
    auto alloc = [&](size_t nfloats) { float* p = ws + off; off += nfloats; return p; };

    float* Xb   = alloc(1048576);           // activations fp32 (N,L,D)
    float* Pb   = alloc(4194304);           // split-K partials / embed scratch
    float* QKVb = alloc(3145728);           // fused QKV fp32 (N,L,1536)
    float* Sb   = alloc(1048576);           // raw chunk KV sums
    float* ksb  = alloc(16384);
    float* qkvB = alloc(4 * QS);            // per-head fused QKV bias
    float* hb   = alloc(8704);              // concat head bias
    bf16* Xh    = (bf16*)alloc(524288);     // activations bf16
    bf16* Ob    = (bf16*)alloc(524288);     // attention out bf16
    bf16* Tb    = (bf16*)alloc(2097152);    // FF intermediate bf16 (N,L,FF)
    bf16* ximgh = (bf16*)alloc(524288);
    bf16* QKVt  = (bf16*)alloc(1572864);    // (NL,1536,512) per-head-grouped
    bf16* Wot   = (bf16*)alloc(524288);     // (NL,512,512)
    bf16* W1t   = (bf16*)alloc(2097152);    // (NL,2048,512)
    bf16* W2t   = (bf16*)alloc(2097152);    // (NL,512,2048)
    bf16* Weit  = (bf16*)alloc(131072);     // (512,512)
    bf16* Whead = (bf16*)alloc(2195456);    // (8576,512)

    const dim3 blk(256);
    const dim3 gAttn(NCHUNK, NHEAD, NB);

    // ---- one setup dispatch: all casts + biases ----
    setup_all<<<dim3(CO_END), blk, 0, stream>>>(
        Wq, Wk, Wv, Wo, W1, W2, W_ei, W_pi, W_pt,
        QKVt, Wot, W1t, W2t, Weit, Whead,
        x_img, ximgh, bq, bk, bv, qkvB, b_pi, b_pt, hb);

    // ---- embedding ----
    gemm16<64, 64><<<dim3(8, 32), blk, 0, stream>>>(
        ximgh, Weit, b_ei, Pb, nullptr, nullptr, NROWS, 512, 512, OP_NONE, 512);
    embed_k<<<NROWS, blk, 0, stream>>>(Pb, x_txt, emb_txt, mask_i, mask_t,
                                       pos_r, pos_c, pos_t, Xb, Xh);

    for (int i = 0; i < NLAYER; ++i) {
        // fused QKV projection + chunk-state reduction (replaces QKV+attn_kv)
        qkv_attn<<<gAttn, blk, 0, stream>>>(
            Xh, QKVt + (size_t)i * 786432, qkvB + i * QS, QKVb, Sb, ksb);

        attn_out<<<gAttn, blk, 0, stream>>>(QKVb, Sb, ksb, Ob);

        // out proj (split-K=2 partials) -> fused reduce+residual+LN1
        gemm16<64, 64><<<dim3(8, 32, 2), blk, 0, stream>>>(
            Ob, Wot + (size_t)i * 262144, nullptr,
            Pb, nullptr, nullptr, NROWS, 512, 512, OP_PART, 256);
        ln_red<<<NROWS, blk, 0, stream>>>(Pb, 2, bo + (size_t)i * DM, Xb,
                                          ln1_s + (size_t)i * DM,
                                          ln1_b + (size_t)i * DM, Xb, Xh);

        // FF1 (gelu fused) -> FF2 (split-K=4) -> fused reduce+residual+LN2
        gemm16<64, 128><<<dim3(16, 32), blk, 0, stream>>>(
            Xh, W1t + (size_t)i * 1048576, b1 + (size_t)i * FFD,
            nullptr, nullptr, Tb, NROWS, 512, FFD, OP_GELU, 512);
        gemm16<64, 64><<<dim3(8, 32, 4), blk, 0, stream>>>(
            Tb, W2t + (size_t)i * 1048576, nullptr,
            Pb, nullptr, nullptr, NROWS, 2048, 512, OP_PART, 512);
        ln_red<<<NROWS, blk, 0, stream>>>(Pb, 4, b2 + (size_t)i * DM, Xb,
                                          ln2_s + (size_t)i * DM,
                                          ln2_b + (size_t)i * DM, Xb, Xh);
    }

    // ---- merged heads: 4-wave 128x128 2-stage + XCD swizzle ----
    float* out = (float*)d_out;
    gemm16<128, 128><<<dim3(16, 67), blk, 0, stream>>>(
        Xh, Whead, hb, out, out + 1048576, nullptr,
        NROWS, 512, NHEADCAT, OP_HEAD, 512);
}

// Round 7
// 598.173 us; speedup vs baseline: 1.1269x; 1.0185x over previous
//
#include <hip/hip_runtime.h>
#include <hip/hip_bf16.h>
#include <math.h>

// Model dims
#define NB 2
#define LSEQ 1024
#define DM 512
#define FFD 2048
#define NHEAD 8
#define DKH 64
#define NLAYER 4
#define VOCAB 8000
#define NCHUNK 16           // L / 64
#define NROWS (NB * LSEQ)   // 2048
#define QS 1536             // fused QKV row stride
#define NHEADCAT 8512       // 512 (img) + 8000 (txt)
#define NHEADPAD 8576       // padded: 512 + 252*32

#define OP_NONE 0
#define OP_GELU 2
#define OP_PART 4   // raw fp32 partial at outF + z*M*Nout (split-K)
#define OP_HEAD 5   // col<512 -> outF (img), else outF2 (txt); grid x=M-tiles!

typedef __attribute__((ext_vector_type(8))) short short8;
typedef __attribute__((ext_vector_type(4))) float f32x4;
typedef __hip_bfloat16 bf16;

// ---------------------------------------------------------------------------
// 32x32 transpose-cast tile: src (K,N) fp32 -> dst (Npad,K) bf16; n>=N -> 0.
// Vectorized: float4 loads (16B/lane), 8B stores.
// ---------------------------------------------------------------------------
__device__ __forceinline__ void cast_tile(
    const float* __restrict__ s, bf16* __restrict__ d, int K, int N,
    int n0, int k0, int tid)
{
    __shared__ float tile[32][33];
    const int r  = tid >> 3;          // k within tile, 0..31
    const int c4 = (tid & 7) * 4;     // n within tile, multiple of 4
    const int n  = n0 + c4;
    float4 v = make_float4(0.f, 0.f, 0.f, 0.f);
    if (n < N)                        // N % 4 == 0, so whole float4 in or out
        v = *(const float4*)(s + (size_t)(k0 + r) * N + n);
    tile[r][c4 + 0] = v.x; tile[r][c4 + 1] = v.y;
    tile[r][c4 + 2] = v.z; tile[r][c4 + 3] = v.w;
    __syncthreads();
    const int nr = tid >> 3;          // n-row for write
    const int kc = (tid & 7) * 4;     // k cols, multiple of 4
    bf16 o[4];
    o[0] = __float2bfloat16(tile[kc + 0][nr]);
    o[1] = __float2bfloat16(tile[kc + 1][nr]);
    o[2] = __float2bfloat16(tile[kc + 2][nr]);
    o[3] = __float2bfloat16(tile[kc + 3][nr]);
    *(unsigned long long*)(d + (size_t)(n0 + nr) * K + k0 + kc) =
        *(const unsigned long long*)o;
    __syncthreads();
}

// ---------------------------------------------------------------------------
// ONE setup dispatch: all weight transposes-casts, x_img cast, bias prep.
// QKV weights stored PER-HEAD-GROUPED: B-row = h*192 + which*64 + (col&63)
// -> a (chunk,head) GEMM block sees [Q_h|K_h|V_h] as 192 contiguous rows.
// ---------------------------------------------------------------------------
#define CO_QKVO 0        // 4096: Wq/Wk/Wv/Wo (4 layers x 4 x 256 tiles)
#define CO_W1   4096     // 4096
#define CO_W2   8192     // 4096
#define CO_WEI  12288    // 256
#define CO_WPI  12544    // 256
#define CO_WPT  12800    // 4032
#define CO_XIMG 16832    // 1024
#define CO_QKVB 17856    // 4
#define CO_HB   17860    // 34
#define CO_END  17894

__global__ __launch_bounds__(256) void setup_all(
    const float* __restrict__ Wq, const float* __restrict__ Wk,
    const float* __restrict__ Wv, const float* __restrict__ Wo,
    const float* __restrict__ W1, const float* __restrict__ W2,
    const float* __restrict__ Wei, const float* __restrict__ Wpi,
    const float* __restrict__ Wpt,
    bf16* __restrict__ QKVt, bf16* __restrict__ Wot,
    bf16* __restrict__ W1t, bf16* __restrict__ W2t,
    bf16* __restrict__ Weit, bf16* __restrict__ Whead,
    const float* __restrict__ x_img, bf16* __restrict__ ximgh,
    const float* __restrict__ bq, const float* __restrict__ bk,
    const float* __restrict__ bv, float* __restrict__ qkvB,
    const float* __restrict__ bpi, const float* __restrict__ bpt,
    float* __restrict__ hb)
{
    const int id = blockIdx.x;
    const int tid = threadIdx.x;

    if (id < CO_W1) {                       // QKVO 512x512 casts
        const int rel = id;
        const int z = rel >> 8, t = rel & 255;
        const int layer = z >> 2, which = z & 3;
        const float* src = (which == 0 ? Wq : which == 1 ? Wk : which == 2 ? Wv : Wo)
                           + (size_t)layer * 262144;
        const int n0 = (t & 15) * 32, k0 = (t >> 4) * 32;
        if (which < 3) {
            const int h = n0 >> 6;
            bf16* dst = QKVt + (size_t)layer * 786432
                      + (size_t)(h * 128 + which * 64) * 512;
            cast_tile(src, dst, 512, 512, n0, k0, tid);
        } else {
            cast_tile(src, Wot + (size_t)layer * 262144, 512, 512, n0, k0, tid);
        }
    } else if (id < CO_W2) {                // W1 (512,2048) x4
        const int rel = id - CO_W1;
        const int z = rel >> 10, t = rel & 1023;
        cast_tile(W1 + (size_t)z * 1048576, W1t + (size_t)z * 1048576,
                  512, 2048, (t & 63) * 32, (t >> 6) * 32, tid);
    } else if (id < CO_WEI) {               // W2 (2048,512) x4
        const int rel = id - CO_W2;
        const int z = rel >> 10, t = rel & 1023;
        cast_tile(W2 + (size_t)z * 1048576, W2t + (size_t)z * 1048576,
                  2048, 512, (t & 15) * 32, (t >> 4) * 32, tid);
    } else if (id < CO_WPI) {               // W_ei
        const int t = id - CO_WEI;
        cast_tile(Wei, Weit, 512, 512, (t & 15) * 32, (t >> 4) * 32, tid);
    } else if (id < CO_WPT) {               // W_pi -> Whead rows 0..511
        const int t = id - CO_WPI;
        cast_tile(Wpi, Whead, 512, 512, (t & 15) * 32, (t >> 4) * 32, tid);
    } else if (id < CO_XIMG) {              // W_pt -> Whead rows 512..8575
        const int t = id - CO_WPT;
        cast_tile(Wpt, Whead + 262144, 512, VOCAB,
                  (t % 252) * 32, (t / 252) * 32, tid);
    } else if (id < CO_QKVB) {              // x_img elementwise cast
        const int i = (id - CO_XIMG) * 256 + tid;   // i < 262144 (x4 floats)
        const float4 v = *(const float4*)(x_img + (size_t)i * 4);
        ximgh[(size_t)i * 4 + 0] = __float2bfloat16(v.x);
        ximgh[(size_t)i * 4 + 1] = __float2bfloat16(v.y);
        ximgh[(size_t)i * 4 + 2] = __float2bfloat16(v.z);
        ximgh[(size_t)i * 4 + 3] = __float2bfloat16(v.w);
    } else if (id < CO_HB) {                // per-head QKV bias: [bq_h|bk_h|bv_h]
        const int z = id - CO_QKVB;
        for (int j = tid; j < QS; j += 256) {
            const int h = j / 192, rem = j - h * 192;
            const int which = rem >> 6, idx = rem & 63;
            const float* bsrc = (which == 0 ? bq : which == 1 ? bk : bv);
            qkvB[z * QS + j] = bsrc[z * DM + h * 64 + idx];
        }
    } else {                                // concat head bias
        const int j = (id - CO_HB) * 256 + tid;
        if (j < NHEADPAD)
            hb[j] = (j < 512) ? bpi[j] : (j < NHEADCAT ? bpt[j - 512] : 0.f);
    }
}

// ---------------------------------------------------------------------------
// bf16 MFMA GEMM (4 waves, 2-stage counted-vmcnt, raw s_barrier) with
// OPERAND-SWAPPED MFMA: acc = mfma(b, a, acc) transposes the C/D mapping
// (m89 layout) so each lane holds 4 CONSECUTIVE COLUMNS of one row per
// register quad -> the C-write is ONE global_store_dwordx4 per 16x16 tile
// (was 4 scattered dwords). Attacks the head GEMM's measured write path:
// WRITE_SIZE 88MB vs 70 ideal (1.27x partial-line amplification) at only
// 1.9 TB/s. New layout: acc[i][j][r] = C[bm+wm+i*16+l16][bn+wn+j*16+quad*4+r].
// OP_HEAD: transposed grid (x = M-tiles) + bijective XCD-chunked swizzle.
// ---------------------------------------------------------------------------
template<int BM, int BN>
__global__ __launch_bounds__(256) void gemm16(
    const bf16* __restrict__ A, const bf16* __restrict__ Bt,
    const float* __restrict__ bias,
    float* __restrict__ outF, float* __restrict__ outF2,
    bf16* __restrict__ outH,
    int M, int K, int Nout, int op, int kslab)
{
    constexpr int WM = BM / 2, WN = BN / 2, MI = WM / 16, NI = WN / 16;
    constexpr int LA = BM / 64, LB = BN / 64;
    constexpr int NL = LA + LB;
    __shared__ bf16 As[2][BM * 32];
    __shared__ bf16 Bs[2][BN * 32];
    const int tid = threadIdx.x;
    const int lane = tid & 63;
    const int wave = tid >> 6;
    const int wm = (wave >> 1) * WM, wn = (wave & 1) * WN;

    int bxi = blockIdx.x, byi = blockIdx.y;
    if (op == OP_HEAD) {
        const int gx = gridDim.x;
        const int nwg = gx * gridDim.y;
        int flat = byi * gx + bxi;
        const int q = nwg >> 3, r = nwg & 7;
        const int xcd = flat & 7, lid = flat >> 3;
        flat = (xcd < r ? xcd * (q + 1) : r * (q + 1) + (xcd - r) * q) + lid;
        bxi = flat % gx;
        byi = flat / gx;
    }
    const int bm = (op == OP_HEAD ? bxi : blockIdx.y) * BM;
    const int bn = (op == OP_HEAD ? byi : blockIdx.x) * BN;
    const int l16 = lane & 15, quad = lane >> 4;

    const int rA = tid >> 2;
    const int c8 = (tid & 3) << 3;

    f32x4 acc[MI][NI];
    #pragma unroll
    for (int i = 0; i < MI; ++i)
        #pragma unroll
        for (int j = 0; j < NI; ++j) acc[i][j] = (f32x4){0.f, 0.f, 0.f, 0.f};

    const bf16* gA = A  + (size_t)(bm + rA) * K + c8;
    const bf16* gB = Bt + (size_t)(bn + rA) * K + c8;
    const int ldsWaveOff = wave * 1024;

    const int kStart = blockIdx.z * kslab;
    const int kEnd = kStart + kslab;

    auto stage = [&](int buf, int k0) {
        #pragma unroll
        for (int i = 0; i < LA; ++i)
            __builtin_amdgcn_global_load_lds(
                (const __attribute__((address_space(1))) void*)(gA + (size_t)i * 64 * K + k0),
                (__attribute__((address_space(3))) void*)((char*)As[buf] + i * 4096 + ldsWaveOff),
                16, 0, 0);
        #pragma unroll
        for (int i = 0; i < LB; ++i)
            __builtin_amdgcn_global_load_lds(
                (const __attribute__((address_space(1))) void*)(gB + (size_t)i * 64 * K + k0),
                (__attribute__((address_space(3))) void*)((char*)Bs[buf] + i * 4096 + ldsWaveOff),
                16, 0, 0);
    };

    stage(0, kStart);
    int cur = 0;
    for (int k0 = kStart; k0 < kEnd; k0 += 32) {
        const bool hasNext = (k0 + 32 < kEnd);
        if (hasNext) {
            stage(cur ^ 1, k0 + 32);
            asm volatile("s_waitcnt vmcnt(%0)" :: "n"(NL) : "memory");
        } else {
            asm volatile("s_waitcnt vmcnt(0)" ::: "memory");
        }
        __builtin_amdgcn_s_barrier();
        short8 a[MI], b[NI];
        #pragma unroll
        for (int i = 0; i < MI; ++i)
            a[i] = *(const short8*)(As[cur] + (size_t)(wm + i * 16 + l16) * 32 + quad * 8);
        #pragma unroll
        for (int j = 0; j < NI; ++j)
            b[j] = *(const short8*)(Bs[cur] + (size_t)(wn + j * 16 + l16) * 32 + quad * 8);
        #pragma unroll
        for (int i = 0; i < MI; ++i)
            #pragma unroll
            for (int j = 0; j < NI; ++j)
                acc[i][j] = __builtin_amdgcn_mfma_f32_16x16x32_bf16(
                    b[j], a[i], acc[i][j], 0, 0, 0);   // swapped: C^T layout
        __builtin_amdgcn_s_barrier();
        cur ^= 1;
    }

    if (op == OP_PART) {
        float* dst = outF + (size_t)blockIdx.z * (size_t)M * Nout;
        #pragma unroll
        for (int i = 0; i < MI; ++i) {
            const int row = bm + wm + i * 16 + l16;
            #pragma unroll
            for (int j = 0; j < NI; ++j) {
                const int colb = bn + wn + j * 16 + quad * 4;
                *(f32x4*)(dst + (size_t)row * Nout + colb) = acc[i][j];
            }
        }
        return;
    }
    if (op == OP_HEAD) {
        #pragma unroll
        for (int i = 0; i < MI; ++i) {
            const int row = bm + wm + i * 16 + l16;
            #pragma unroll
            for (int j = 0; j < NI; ++j) {
                const int colb = bn + wn + j * 16 + quad * 4;
                const bool cok = (colb < NHEADCAT);   // 8512 % 4 == 0
                if (!cok) continue;
                const float4 bz = *(const float4*)(bias + colb);
                f32x4 v = acc[i][j];
                v[0] += bz.x; v[1] += bz.y; v[2] += bz.z; v[3] += bz.w;
                if (colb < 512)
                    *(f32x4*)(outF + (size_t)row * 512 + colb) = v;
                else
                    *(f32x4*)(outF2 + (size_t)row * VOCAB + (colb - 512)) = v;
            }
        }
        return;
    }

    #pragma unroll
    for (int i = 0; i < MI; ++i) {
        const int row = bm + wm + i * 16 + l16;
        #pragma unroll
        for (int j = 0; j < NI; ++j) {
            const int colb = bn + wn + j * 16 + quad * 4;
            if (colb >= Nout) continue;               // Nout % 4 == 0
            const float4 bz = bias ? *(const float4*)(bias + colb)
                                   : make_float4(0.f, 0.f, 0.f, 0.f);
            float v[4];
            #pragma unroll
            for (int r = 0; r < 4; ++r) {
                v[r] = acc[i][j][r] + ((const float*)&bz)[r];
                if (op == OP_GELU)
                    v[r] = 0.5f * v[r] * (1.f + erff(v[r] * 0.70710678118654752f));
            }
            if (outF)
                *(f32x4*)(outF + (size_t)row * Nout + colb) =
                    (f32x4){v[0], v[1], v[2], v[3]};
            if (outH) {
                bf16 o[4];
                o[0] = __float2bfloat16(v[0]); o[1] = __float2bfloat16(v[1]);
                o[2] = __float2bfloat16(v[2]); o[3] = __float2bfloat16(v[3]);
                *(unsigned long long*)(outH + (size_t)row * Nout + colb) =
                    *(const unsigned long long*)o;
            }
        }
    }
}

// ---------------------------------------------------------------------------
// FUSED QKV projection + attn chunk-state kernel. Grid (NCHUNK, NHEAD, NB).
// Operand-swapped MFMA epilogue: per (i,j) one float4 store (was 4 dwords).
// ---------------------------------------------------------------------------
__global__ __launch_bounds__(256) void qkv_attn(
    const bf16* __restrict__ A, const bf16* __restrict__ Bt,
    const float* __restrict__ bias,
    float* __restrict__ QKVb, float* __restrict__ S, float* __restrict__ ks)
{
    // LDS plan: [0,8K) As[2][64*32] bf16 | [8K,32K) Bs[2][192*32] bf16
    // overlay after K-loop: [0,16K) sK f32[64][64] | [16K,32K) sV | [32K,33K) part
    __shared__ char smem[33792];
    const int c = blockIdx.x, h = blockIdx.y, n = blockIdx.z;
    const int tid = threadIdx.x;
    const int lane = tid & 63;
    const int wave = tid >> 6;
    const int l16 = lane & 15, quad = lane >> 4;
    const int r0 = n * LSEQ + c * 64;
    const int wn = wave * 48;                 // wave's 48-col slice of 192

    const bf16* Bh = Bt + (size_t)(h * 192) * 512;
    const float* bh = bias + h * 192;

    f32x4 acc[4][3];
    #pragma unroll
    for (int i = 0; i < 4; ++i)
        #pragma unroll
        for (int j = 0; j < 3; ++j) acc[i][j] = (f32x4){0.f, 0.f, 0.f, 0.f};

    const bf16* gA = A + (size_t)(r0 + (tid >> 2)) * 512 + ((tid & 3) << 3);
    const int ldsWaveOff = wave * 1024;

    auto stage = [&](int buf, int k0) {
        __builtin_amdgcn_global_load_lds(
            (const __attribute__((address_space(1))) void*)(gA + k0),
            (__attribute__((address_space(3))) void*)(smem + buf * 4096 + ldsWaveOff),
            16, 0, 0);
        #pragma unroll
        for (int p = 0; p < 3; ++p)
            __builtin_amdgcn_global_load_lds(
                (const __attribute__((address_space(1))) void*)(
                    Bh + (size_t)(p * 64 + (tid >> 2)) * 512 + ((tid & 3) << 3) + k0),
                (__attribute__((address_space(3))) void*)(
                    smem + 8192 + buf * 12288 + p * 4096 + ldsWaveOff),
                16, 0, 0);
    };

    stage(0, 0);
    int cur = 0;
    for (int k0 = 0; k0 < 512; k0 += 32) {
        if (k0 + 32 < 512) {
            stage(cur ^ 1, k0 + 32);
            asm volatile("s_waitcnt vmcnt(4)" ::: "memory");
        } else {
            asm volatile("s_waitcnt vmcnt(0)" ::: "memory");
        }
        __builtin_amdgcn_s_barrier();
        const bf16* Asb = (const bf16*)(smem + cur * 4096);
        const bf16* Bsb = (const bf16*)(smem + 8192 + cur * 12288);
        short8 a[4], b[3];
        #pragma unroll
        for (int i = 0; i < 4; ++i)
            a[i] = *(const short8*)(Asb + (i * 16 + l16) * 32 + quad * 8);
        #pragma unroll
        for (int j = 0; j < 3; ++j)
            b[j] = *(const short8*)(Bsb + (wn + j * 16 + l16) * 32 + quad * 8);
        #pragma unroll
        for (int i = 0; i < 4; ++i)
            #pragma unroll
            for (int j = 0; j < 3; ++j)
                acc[i][j] = __builtin_amdgcn_mfma_f32_16x16x32_bf16(
                    b[j], a[i], acc[i][j], 0, 0, 0);   // swapped: C^T layout
        __builtin_amdgcn_s_barrier();
        cur ^= 1;
    }
    __syncthreads();                          // LDS reuse boundary

    float* sK   = (float*)smem;               // [64][64]
    float* sV   = (float*)(smem + 16384);     // [64][64]
    float* part = (float*)(smem + 32768);     // [4][64]

    // epilogue: bias + elu+1 (Q,K) -> global QKVb (float4); stash K,V in LDS
    #pragma unroll
    for (int i = 0; i < 4; ++i) {
        const int row = i * 16 + l16;
        #pragma unroll
        for (int j = 0; j < 3; ++j) {
            const int colb = wn + j * 16 + quad * 4;  // 0..188, mult of 4
            const float4 bz = *(const float4*)(bh + colb);
            float v[4];
            #pragma unroll
            for (int r = 0; r < 4; ++r) {
                v[r] = acc[i][j][r] + ((const float*)&bz)[r];
                if (colb < 128) v[r] = (v[r] > 0.f) ? v[r] + 1.f : expf(v[r]);
            }
            int gcolb;
            if (colb < 64)       gcolb = h * 64 + colb;
            else if (colb < 128) gcolb = 512 + h * 64 + (colb - 64);
            else                 gcolb = 1024 + h * 64 + (colb - 128);
            *(f32x4*)(QKVb + (size_t)(r0 + row) * QS + gcolb) =
                (f32x4){v[0], v[1], v[2], v[3]};
            if (colb >= 128)
                *(f32x4*)(sV + row * 64 + (colb - 128)) = (f32x4){v[0], v[1], v[2], v[3]};
            else if (colb >= 64)
                *(f32x4*)(sK + row * 64 + (colb - 64))  = (f32x4){v[0], v[1], v[2], v[3]};
        }
    }
    __syncthreads();

    // attn_kv reduction: S_c = K^T V, ksum
    const int e = tid & 63, dq = tid >> 6;
    float s[16] = {};
    for (int l = 0; l < 64; ++l) {
        const float vv = sV[l * 64 + e];
        const float4 k0v = *(const float4*)(sK + l * 64 + dq * 16 + 0);
        const float4 k1v = *(const float4*)(sK + l * 64 + dq * 16 + 4);
        const float4 k2v = *(const float4*)(sK + l * 64 + dq * 16 + 8);
        const float4 k3v = *(const float4*)(sK + l * 64 + dq * 16 + 12);
        s[0]  = fmaf(k0v.x, vv, s[0]);  s[1]  = fmaf(k0v.y, vv, s[1]);
        s[2]  = fmaf(k0v.z, vv, s[2]);  s[3]  = fmaf(k0v.w, vv, s[3]);
        s[4]  = fmaf(k1v.x, vv, s[4]);  s[5]  = fmaf(k1v.y, vv, s[5]);
        s[6]  = fmaf(k1v.z, vv, s[6]);  s[7]  = fmaf(k1v.w, vv, s[7]);
        s[8]  = fmaf(k2v.x, vv, s[8]);  s[9]  = fmaf(k2v.y, vv, s[9]);
        s[10] = fmaf(k2v.z, vv, s[10]); s[11] = fmaf(k2v.w, vv, s[11]);
        s[12] = fmaf(k3v.x, vv, s[12]); s[13] = fmaf(k3v.y, vv, s[13]);
        s[14] = fmaf(k3v.z, vv, s[14]); s[15] = fmaf(k3v.w, vv, s[15]);
    }
    const size_t sb = (((size_t)(n * NHEAD + h)) * NCHUNK + c) * 4096;
    #pragma unroll
    for (int i = 0; i < 16; ++i) S[sb + (size_t)(dq * 16 + i) * 64 + e] = s[i];

    float kp = 0.f;
    #pragma unroll
    for (int i = 0; i < 16; ++i) kp += sK[(dq * 16 + i) * 64 + e];
    part[dq * 64 + e] = kp;
    __syncthreads();
    if (tid < 64)
        ks[(((size_t)(n * NHEAD + h)) * NCHUNK + c) * 64 + tid] =
            part[tid] + part[64 + tid] + part[128 + tid] + part[192 + tid];
}

// ---------------------------------------------------------------------------
// Embedding combine. gI = x_img @ W_ei + b_ei (precomputed fp32).
// ---------------------------------------------------------------------------
__global__ __launch_bounds__(256) void embed_k(
    const float* __restrict__ gI, const int* __restrict__ xt,
    const float* __restrict__ emb,
    const float* __restrict__ mi, const float* __restrict__ mt,
    const float* __restrict__ pr, const float* __restrict__ pc,
    const float* __restrict__ pt, float* __restrict__ X, bf16* __restrict__ Xh)
{
    const int row = blockIdx.x;
    const float prv = pr[row], pcv = pc[row], ptv = pt[row];
    const float miv = mi[row], mtv = mt[row];
    const int tok = xt[row];
    const float LOG1E4 = 9.2103403719761836f;
    const float LI127 = LOG1E4 / 127.f;
    const float LI255 = LOG1E4 / 255.f;

    for (int d = threadIdx.x; d < DM; d += 256) {
        float ip;
        if (d < 128)       ip = sinf(prv * expf(-(float)d * LI127));
        else if (d < 256)  ip = cosf(prv * expf(-(float)(d - 128) * LI127));
        else if (d < 384)  ip = sinf(pcv * expf(-(float)(d - 256) * LI127));
        else               ip = cosf(pcv * expf(-(float)(d - 384) * LI127));
        float tp;
        if (d < 256) tp = sinf(ptv * expf(-(float)d * LI255));
        else         tp = cosf(ptv * expf(-(float)(d - 256) * LI255));
        const float v = miv * (gI[(size_t)row * DM + d] + ip)
                      + mtv * (emb[(size_t)tok * DM + d] + tp);
        X[(size_t)row * DM + d] = v;
        Xh[(size_t)row * DM + d] = __float2bfloat16(v);
    }
}

// ---------------------------------------------------------------------------
// Fused partial-sum + bias + residual + LayerNorm (out may alias res).
// ---------------------------------------------------------------------------
__global__ __launch_bounds__(256) void ln_red(
    const float* __restrict__ P, int nP,
    const float* __restrict__ bias, const float* __restrict__ res,
    const float* __restrict__ g, const float* __restrict__ b,
    float* __restrict__ out, bf16* __restrict__ outh)
{
    const int row = blockIdx.x;
    const int tid = threadIdx.x;
    const int lane = tid & 63, wv = tid >> 6;
    const size_t base = (size_t)row * DM;
    float x0 = res[base + tid] + bias[tid];
    float x1 = res[base + tid + 256] + bias[tid + 256];
    for (int p = 0; p < nP; ++p) {
        x0 += P[(size_t)p * 1048576 + base + tid];
        x1 += P[(size_t)p * 1048576 + base + tid + 256];
    }
    __shared__ float redA[4];
    __shared__ float redB[4];
    float s = x0 + x1;
    #pragma unroll
    for (int off = 32; off > 0; off >>= 1) s += __shfl_down(s, off);
    if (lane == 0) redA[wv] = s;
    __syncthreads();
    const float mean = (redA[0] + redA[1] + redA[2] + redA[3]) * (1.f / (float)DM);
    const float d0 = x0 - mean, d1 = x1 - mean;
    float v = d0 * d0 + d1 * d1;
    #pragma unroll
    for (int off = 32; off > 0; off >>= 1) v += __shfl_down(v, off);
    if (lane == 0) redB[wv] = v;
    __syncthreads();
    const float var = (redB[0] + redB[1] + redB[2] + redB[3]) * (1.f / (float)DM);
    const float rstd = rsqrtf(var + 1e-5f);
    const float y0 = d0 * rstd * g[tid] + b[tid];
    const float y1 = d1 * rstd * g[tid + 256] + b[tid + 256];
    out[base + tid]        = y0;
    out[base + tid + 256]  = y1;
    outh[base + tid]       = __float2bfloat16(y0);
    outh[base + tid + 256] = __float2bfloat16(y1);
}

// ---------------------------------------------------------------------------
// attn_out: O = Q@S_pre + tril(Q@K^T)@V. Prefix S_pre summed inline from raw
// chunk states of chunks < c (exclusive). Grid (16,8,2). (Unchanged.)
// ---------------------------------------------------------------------------
__global__ __launch_bounds__(256) void attn_out(
    const float* __restrict__ QKV, const float* __restrict__ S,
    const float* __restrict__ ks, bf16* __restrict__ O)
{
    const int c = blockIdx.x, h = blockIdx.y, n = blockIdx.z;
    const int tid = threadIdx.x;
    __shared__ float sQt[64][64];
    __shared__ float sKt[64][64];
    __shared__ float sV [64][64];
    __shared__ float sS [64][64];
    __shared__ float sPt[64][65];
    __shared__ float skp[64];

    const size_t nhS = ((size_t)(n * NHEAD + h)) * NCHUNK * 4096;
    const size_t nhK = ((size_t)(n * NHEAD + h)) * NCHUNK * 64;

    {
        float4 aS[4] = {};
        for (int cc = 0; cc < c; ++cc) {
            const float* Sc = S + nhS + (size_t)cc * 4096;
            #pragma unroll
            for (int i = 0; i < 4; ++i) {
                const float4 t = *(const float4*)(Sc + i * 1024 + tid * 4);
                aS[i].x += t.x; aS[i].y += t.y; aS[i].z += t.z; aS[i].w += t.w;
            }
        }
        float* sSf = &sS[0][0];
        #pragma unroll
        for (int i = 0; i < 4; ++i)
            *(float4*)(sSf + i * 1024 + tid * 4) = aS[i];
        if (tid < 64) {
            float kp = 0.f;
            for (int cc = 0; cc < c; ++cc) kp += ks[nhK + cc * 64 + tid];
            skp[tid] = kp;
        }
    }

    const int lr = tid >> 4;
    const int c4 = (tid & 15) * 4;
    #pragma unroll
    for (int it = 0; it < 4; ++it) {
        const int row = it * 16 + lr;
        const size_t gb = ((size_t)(n * LSEQ + c * 64 + row)) * QS + h * DKH + c4;
        const float4 q4 = *(const float4*)(QKV + gb);
        const float4 k4 = *(const float4*)(QKV + gb + 512);
        const float4 v4 = *(const float4*)(QKV + gb + 1024);
        sQt[c4 + 0][row] = q4.x; sQt[c4 + 1][row] = q4.y;
        sQt[c4 + 2][row] = q4.z; sQt[c4 + 3][row] = q4.w;
        sKt[c4 + 0][row] = k4.x; sKt[c4 + 1][row] = k4.y;
        sKt[c4 + 2][row] = k4.z; sKt[c4 + 3][row] = k4.w;
        *(float4*)&sV[row][c4] = v4;
    }
    __syncthreads();

    const int m4 = (tid & 15) * 4;
    const int lg = tid >> 4;
    {
        float p[4][4] = {};
        for (int d = 0; d < 64; ++d) {
            const float4 k4 = *(const float4*)&sKt[d][m4];
            const float4 q4 = *(const float4*)&sQt[d][lg * 4];
            p[0][0] = fmaf(q4.x, k4.x, p[0][0]); p[0][1] = fmaf(q4.x, k4.y, p[0][1]);
            p[0][2] = fmaf(q4.x, k4.z, p[0][2]); p[0][3] = fmaf(q4.x, k4.w, p[0][3]);
            p[1][0] = fmaf(q4.y, k4.x, p[1][0]); p[1][1] = fmaf(q4.y, k4.y, p[1][1]);
            p[1][2] = fmaf(q4.y, k4.z, p[1][2]); p[1][3] = fmaf(q4.y, k4.w, p[1][3]);
            p[2][0] = fmaf(q4.z, k4.x, p[2][0]); p[2][1] = fmaf(q4.z, k4.y, p[2][1]);
            p[2][2] = fmaf(q4.z, k4.z, p[2][2]); p[2][3] = fmaf(q4.z, k4.w, p[2][3]);
            p[3][0] = fmaf(q4.w, k4.x, p[3][0]); p[3][1] = fmaf(q4.w, k4.y, p[3][1]);
            p[3][2] = fmaf(q4.w, k4.z, p[3][2]); p[3][3] = fmaf(q4.w, k4.w, p[3][3]);
        }
        #pragma unroll
        for (int jj = 0; jj < 4; ++jj)
            #pragma unroll
            for (int j = 0; j < 4; ++j)
                sPt[m4 + jj][lg * 4 + j] = p[j][jj];
    }
    __syncthreads();

    float acc[4][4] = {};
    float z[4] = {};
    const int lmax = lg * 4 + 3;
    for (int m = 0; m <= lmax; ++m) {
        const float4 v4 = *(const float4*)&sV[m][m4];
        #pragma unroll
        for (int j = 0; j < 4; ++j) {
            const int l = lg * 4 + j;
            float p = sPt[m][l];
            p = (m <= l) ? p : 0.f;
            z[j] += p;
            acc[j][0] = fmaf(p, v4.x, acc[j][0]);
            acc[j][1] = fmaf(p, v4.y, acc[j][1]);
            acc[j][2] = fmaf(p, v4.z, acc[j][2]);
            acc[j][3] = fmaf(p, v4.w, acc[j][3]);
        }
    }
    for (int d = 0; d < 64; ++d) {
        const float4 s4 = *(const float4*)&sS[d][m4];
        const float4 q4 = *(const float4*)&sQt[d][lg * 4];
        const float kp = skp[d];
        z[0] = fmaf(q4.x, kp, z[0]); z[1] = fmaf(q4.y, kp, z[1]);
        z[2] = fmaf(q4.z, kp, z[2]); z[3] = fmaf(q4.w, kp, z[3]);
        acc[0][0] = fmaf(q4.x, s4.x, acc[0][0]); acc[0][1] = fmaf(q4.x, s4.y, acc[0][1]);
        acc[0][2] = fmaf(q4.x, s4.z, acc[0][2]); acc[0][3] = fmaf(q4.x, s4.w, acc[0][3]);
        acc[1][0] = fmaf(q4.y, s4.x, acc[1][0]); acc[1][1] = fmaf(q4.y, s4.y, acc[1][1]);
        acc[1][2] = fmaf(q4.y, s4.z, acc[1][2]); acc[1][3] = fmaf(q4.y, s4.w, acc[1][3]);
        acc[2][0] = fmaf(q4.z, s4.x, acc[2][0]); acc[2][1] = fmaf(q4.z, s4.y, acc[2][1]);
        acc[2][2] = fmaf(q4.z, s4.z, acc[2][2]); acc[2][3] = fmaf(q4.z, s4.w, acc[2][3]);
        acc[3][0] = fmaf(q4.w, s4.x, acc[3][0]); acc[3][1] = fmaf(q4.w, s4.y, acc[3][1]);
        acc[3][2] = fmaf(q4.w, s4.z, acc[3][2]); acc[3][3] = fmaf(q4.w, s4.w, acc[3][3]);
    }
    #pragma unroll
    for (int j = 0; j < 4; ++j) {
        const int l = lg * 4 + j;
        const float rz = 1.f / (z[j] + 1e-6f);
        const size_t ob = ((size_t)(n * LSEQ + c * 64 + l)) * DM + h * DKH + m4;
        O[ob + 0] = __float2bfloat16(acc[j][0] * rz);
        O[ob + 1] = __float2bfloat16(acc[j][1] * rz);
        O[ob + 2] = __float2bfloat16(acc[j][2] * rz);
        O[ob + 3] = __float2bfloat16(acc[j][3] * rz);
    }
}

// ---------------------------------------------------------------------------
extern "C" void kernel_launch(void* const* d_in, const int* in_sizes, int n_in,
                              void* d_out, int out_size, void* d_ws, size_t ws_size,
                              hipStream_t stream)
{
    const float* x_img   = (const float*)d_in[0];
    const int*   x_txt   = (const int*)  d_in[1];
    const float* mask_i  = (const float*)d_in[2];
    const float* mask_t  = (const float*)d_in[3];
    const float* pos_r   = (const float*)d_in[4];
    const float* pos_c   = (const float*)d_in[5];
    const float* pos_t   = (const float*)d_in[6];
    const float* W_ei    = (const float*)d_in[7];
    const float* b_ei    = (const float*)d_in[8];
    const float* emb_txt = (const float*)d_in[9];
    const float* Wq      = (const float*)d_in[10];
    const float* bq      = (const float*)d_in[11];
    const float* Wk      = (const float*)d_in[12];
    const float* bk      = (const float*)d_in[13];
    const float* Wv      = (const float*)d_in[14];
    const float* bv      = (const float*)d_in[15];
    const float* Wo      = (const float*)d_in[16];
    const float* bo      = (const float*)d_in[17];
    const float* W1      = (const float*)d_in[18];
    const float* b1      = (const float*)d_in[19];
    const float* W2      = (const float*)d_in[20];
    const float* b2      = (const float*)d_in[21];
    const float* ln1_s   = (const float*)d_in[22];
    const float* ln1_b   = (const float*)d_in[23];
    const float* ln2_s   = (const float*)d_in[24];
    const float* ln2_b   = (const float*)d_in[25];
    const float* W_pi    = (const float*)d_in[26];
    const float* b_pi    = (const float*)d_in[27];
    const float* W_pt    = (const float*)d_in[28];
    const float* b_pt    = (const float*)d_in[29];

    float* ws = (float*)d_ws;
    size_t off = 0;
    auto alloc = [&](size_t nfloats) { float* p = ws + off; off += nfloats; return p; };

    float* Xb   = alloc(1048576);           // activations fp32 (N,L,D)
    float* Pb   = alloc(4194304);           // split-K partials / embed scratch
    float* QKVb = alloc(3145728);           // fused QKV fp32 (N,L,1536)
    float* Sb   = alloc(1048576);           // raw chunk KV sums
    float* ksb  = alloc(16384);
    float* qkvB = alloc(4 * QS);            // per-head fused QKV bias
    float* hb   = alloc(8704);              // concat head bias
    bf16* Xh    = (bf16*)alloc(524288);     // activations bf16
    bf16* Ob    = (bf16*)alloc(524288);     // attention out bf16
    bf16* Tb    = (bf16*)alloc(2097152);    // FF intermediate bf16 (N,L,FF)
    bf16* ximgh = (bf16*)alloc(524288);
    bf16* QKVt  = (bf16*)alloc(1572864);    // (NL,1536,512) per-head-grouped
    bf16* Wot   = (bf16*)alloc(524288);     // (NL,512,512)
    bf16* W1t   = (bf16*)alloc(2097152);    // (NL,2048,512)
    bf16* W2t   = (bf16*)alloc(2097152);    // (NL,512,2048)
    bf16* Weit  = (bf16*)alloc(131072);     // (512,512)
    bf16* Whead = (bf16*)alloc(2195456);    // (8576,512)

    const dim3 blk(256);
    const dim3 gAttn(NCHUNK, NHEAD, NB);

    // ---- one setup dispatch: all casts + biases ----
    setup_all<<<dim3(CO_END), blk, 0, stream>>>(
        Wq, Wk, Wv, Wo, W1, W2, W_ei, W_pi, W_pt,
        QKVt, Wot, W1t, W2t, Weit, Whead,
        x_img, ximgh, bq, bk, bv, qkvB, b_pi, b_pt, hb);

    // ---- embedding ----
    gemm16<64, 64><<<dim3(8, 32), blk, 0, stream>>>(
        ximgh, Weit, b_ei, Pb, nullptr, nullptr, NROWS, 512, 512, OP_NONE, 512);
    embed_k<<<NROWS, blk, 0, stream>>>(Pb, x_txt, emb_txt, mask_i, mask_t,
                                       pos_r, pos_c, pos_t, Xb, Xh);

    for (int i = 0; i < NLAYER; ++i) {
        // fused QKV projection + chunk-state reduction (replaces QKV+attn_kv)
        qkv_attn<<<gAttn, blk, 0, stream>>>(
            Xh, QKVt + (size_t)i * 786432, qkvB + i * QS, QKVb, Sb, ksb);

        attn_out<<<gAttn, blk, 0, stream>>>(QKVb, Sb, ksb, Ob);

        // out proj (split-K=2 partials) -> fused reduce+residual+LN1
        gemm16<64, 64><<<dim3(8, 32, 2), blk, 0, stream>>>(
            Ob, Wot + (size_t)i * 262144, nullptr,
            Pb, nullptr, nullptr, NROWS, 512, 512, OP_PART, 256);
        ln_red<<<NROWS, blk, 0, stream>>>(Pb, 2, bo + (size_t)i * DM, Xb,
                                          ln1_s + (size_t)i * DM,
                                          ln1_b + (size_t)i * DM, Xb, Xh);

        // FF1 (gelu fused) -> FF2 (split-K=4) -> fused reduce+residual+LN2
        gemm16<64, 128><<<dim3(16, 32), blk, 0, stream>>>(
            Xh, W1t + (size_t)i * 1048576, b1 + (size_t)i * FFD,
            nullptr, nullptr, Tb, NROWS, 512, FFD, OP_GELU, 512);
        gemm16<64, 64><<<dim3(8, 32, 4), blk, 0, stream>>>(
            Tb, W2t + (size_t)i * 1048576, nullptr,
            Pb, nullptr, nullptr, NROWS, 2048, 512, OP_PART, 512);
        ln_red<<<NROWS, blk, 0, stream>>>(Pb, 4, b2 + (size_t)i * DM, Xb,
                                          ln2_s + (size_t)i * DM,
                                          ln2_b + (size_t)i * DM, Xb, Xh);
    }

    // ---- merged heads: 4-wave 128x128 2-stage + XCD swizzle ----
    float* out = (float*)d_out;
    gemm16<128, 128><<<dim3(16, 67), blk, 0, stream>>>(
        Xh, Whead, hb, out, out + 1048576, nullptr,
        NROWS, 512, NHEADCAT, OP_HEAD, 512);
}